// Round 7
// baseline (83.873 us; speedup 1.0000x reference)
//
#include <hip/hip_runtime.h>
#include <hip/hip_bf16.h>

typedef __attribute__((ext_vector_type(8))) short short8;
typedef __attribute__((ext_vector_type(8))) float f32x8;
typedef __attribute__((ext_vector_type(4))) float f32x4;
typedef unsigned short u16;
typedef unsigned int u32;

#define BQ 8
#define LL 2048
#define NN 1024
#define HH 64
#define BL (BQ * LL) /* 16384 */
#define PART_STRIDE 1056  /* floats per attn partial: 16 m + 16 l + 16x64 O */
#define QSCALE 0.0450842213f  /* (1/32) * log2(e): exp2-domain softmax */

static __device__ __forceinline__ u16 f2bf(float f) {
  union { float f; unsigned int u; } cv;
  cv.f = f;
  unsigned int u = cv.u;
  unsigned int rounded = u + 0x7FFFu + ((u >> 16) & 1u);  // RNE
  return (u16)(rounded >> 16);
}

static __device__ __forceinline__ float exp2x(float x) {
  return __builtin_amdgcn_exp2f(x);
}

// pack 8 f32 -> 8 bf16 by truncation (1 v_perm per 2 elements)
static __device__ __forceinline__ short8 pack_bf16(f32x8 v) {
  short8 o;
  u32* op = (u32*)&o;
#pragma unroll
  for (int w = 0; w < 4; ++w) {
    op[w] = __builtin_amdgcn_perm(__float_as_uint(v[2 * w + 1]),
                                  __float_as_uint(v[2 * w]), 0x07060302u);
  }
  return o;
}

// async global -> LDS, 16B per lane; lds dest must be wave-uniform base
static __device__ __forceinline__ void gload_lds16(const u16* g, u16* l) {
  __builtin_amdgcn_global_load_lds(
      (const __attribute__((address_space(1))) unsigned int*)g,
      (__attribute__((address_space(3))) unsigned int*)l, 16, 0, 0);
}

// ---------------------------------------------------------------------------
// Kernel 0: pack W into MFMA B-fragment order (unchanged).
// ---------------------------------------------------------------------------
__global__ __launch_bounds__(256) void wtp_pack(const float* __restrict__ Wq,
                                                const float* __restrict__ Wk,
                                                const float* __restrict__ Wv,
                                                u16* __restrict__ wtp) {
  int gid = blockIdx.x * 256 + threadIdx.x;   // [0, 384*64)
  int f = gid >> 6;
  int l = gid & 63;
  int m = f >> 7;
  int rem = f & 127;
  int nf = rem >> 5;
  int ks = rem & 31;
  int r = l & 15;
  int g = l >> 4;
  const float* src = (m == 0) ? Wq : (m == 1) ? Wk : Wv;
  short8 o;
#pragma unroll
  for (int j = 0; j < 8; ++j)
    o[j] = (short)f2bf(src[(ks * 32 + 8 * g + j) * HH + nf * 16 + r]);
  *(short8*)&wtp[f * 512 + l * 8] = o;
}

// ---------------------------------------------------------------------------
// Kernel 1: qkv projection, LDS-staged GEMM (unchanged except q-scale now
// folds log2(e) for exp2-domain softmax).
// ---------------------------------------------------------------------------
__global__ __launch_bounds__(512, 4) void qkv_proj(const float* __restrict__ x,
                                                   const u16* __restrict__ wtp,
                                                   u16* __restrict__ qs,
                                                   u16* __restrict__ ks_,
                                                   u16* __restrict__ vsT) {
  __shared__ u16 xs[2][64 * 72];     // x tile, row stride 72
  __shared__ u16 ws[2][24 * 512];    // W frags: c = F*2 + ks, frag-linear

  const int row0 = blockIdx.x * 64;
  const int tid = threadIdx.x;
  const int wv = tid >> 6;
  const int lane = tid & 63;
  const int r = lane & 15;
  const int g = lane >> 4;
  const int ms = wv >> 2;            // 32-row half
  const int fq = wv & 3;             // 3-F quarter

  const int srow = tid >> 3;         // 0..63
  const int scol = (tid & 7) * 8;    // 0..56
  const float* xsrc = x + (row0 + srow) * NN + scol;

  f32x4 acc[2][3] = {};

  {
    f32x8 xv = *(const f32x8*)xsrc;
    *(short8*)&xs[0][srow * 72 + scol] = pack_bf16(xv);
#pragma unroll
    for (int j = 0; j < 3; ++j) {
      int c = wv * 3 + j;
      int F = c >> 1, ks = c & 1;
      int gf = F * 32 + ks;
      gload_lds16(wtp + gf * 512 + lane * 8, &ws[0][c * 512]);
    }
  }
  __syncthreads();

  int cur = 0;
  for (int kc = 0; kc < 16; ++kc) {
    f32x8 xnv;
    if (kc < 15) {
      xnv = *(const f32x8*)(xsrc + (kc + 1) * 64);
#pragma unroll
      for (int j = 0; j < 3; ++j) {
        int c = wv * 3 + j;
        int F = c >> 1, ks = c & 1;
        int gf = F * 32 + (kc + 1) * 2 + ks;
        gload_lds16(wtp + gf * 512 + lane * 8, &ws[cur ^ 1][c * 512]);
      }
    }
#pragma unroll
    for (int ks = 0; ks < 2; ++ks) {
      short8 a[2];
#pragma unroll
      for (int mf = 0; mf < 2; ++mf)
        a[mf] = *(const short8*)&xs[cur][(ms * 32 + mf * 16 + r) * 72 + ks * 32 + 8 * g];
#pragma unroll
      for (int i = 0; i < 3; ++i) {
        int c = (fq * 3 + i) * 2 + ks;
        short8 bfr = *(const short8*)&ws[cur][c * 512 + lane * 8];
#pragma unroll
        for (int mf = 0; mf < 2; ++mf)
          acc[mf][i] = __builtin_amdgcn_mfma_f32_16x16x32_bf16(a[mf], bfr, acc[mf][i], 0, 0, 0);
      }
    }
    if (kc < 15)
      *(short8*)&xs[cur ^ 1][srow * 72 + scol] = pack_bf16(xnv);
    __syncthreads();
    cur ^= 1;
  }

  const int b = row0 >> 11;
  const int kvloc = row0 & (LL - 1);
  u16* vt = xs[0];
#pragma unroll
  for (int mf = 0; mf < 2; ++mf) {
#pragma unroll
    for (int i = 0; i < 3; ++i) {
      const int F = fq * 3 + i, m = F >> 2, nf = F & 3;
      const int rowb = row0 + ms * 32 + mf * 16;
      if (m == 0) {
#pragma unroll
        for (int rr = 0; rr < 4; ++rr)
          qs[(rowb + 4 * g + rr) * HH + nf * 16 + r] = f2bf(acc[mf][i][rr] * QSCALE);
      } else if (m == 1) {
#pragma unroll
        for (int rr = 0; rr < 4; ++rr)
          ks_[(rowb + 4 * g + rr) * HH + nf * 16 + r] = f2bf(acc[mf][i][rr]);
      } else {
#pragma unroll
        for (int rr = 0; rr < 4; ++rr)
          vt[(nf * 16 + r) * 72 + ms * 32 + mf * 16 + 4 * g + rr] = f2bf(acc[mf][i][rr]);
      }
    }
  }
  __syncthreads();
  if (tid < 256) {
    const int h = tid >> 2;
    const int seg = (tid & 3) * 16;
    const u16* s = &vt[h * 72 + seg];
    u16* d = &vsT[(b * HH + h) * LL + kvloc + seg];
    *(short8*)d = *(short8*)s;
    *(short8*)(d + 8) = *(short8*)(s + 8);
  }
}

// ---------------------------------------------------------------------------
// Kernel 2: causal flash attention with 2-way kv-split for long q-tiles.
// Block = (16-row q-tile, kv-chunk, batch); 4 waves, wave w does tiles
// t0+w, t0+w+4, ... with private online-softmax state (exp2 domain).
// cid<64: qt=64+cid chunk0 [0,16); cid in [64,128): qt=191-cid chunk1
// [16,nt); cid>=128: qt=191-cid single [0,nt). Split blocks emit f32
// partials (m,l,O) to ws; attn_merge combines.
// ---------------------------------------------------------------------------
__global__ __launch_bounds__(256, 8) void attn(const u16* __restrict__ qs,
                                               const u16* __restrict__ ks,
                                               const u16* __restrict__ vsT,
                                               float* __restrict__ out,
                                               float* __restrict__ part) {
  __shared__ union {
    u16 P[4][16 * 72];
    struct { float oM[4][16][64]; float ml[4][2][16]; } mg;
  } sm;

  const int bi = blockIdx.x;
  const int cid = bi >> 3;
  const int b = bi & 7;                // batch -> XCD pinning
  int qt, t0, t1, chunk;
  if (cid < 64) {
    qt = 64 + cid; chunk = 0; t0 = 0; t1 = 16;
  } else {
    qt = 191 - cid;
    const int nt = (qt + 4) >> 2;      // ceil((qt+1)/4)
    if (cid < 128) { chunk = 1; t0 = 16; t1 = nt; }
    else           { chunk = -1; t0 = 0; t1 = nt; }
  }
  const int q0 = qt * 16;

  const int tid = threadIdx.x;
  const int lane = tid & 63;
  const int wv = tid >> 6;
  const int r = lane & 15;
  const int g = lane >> 4;

  const u16* qrow = &qs[(b * LL + q0 + r) * HH + 8 * g];
  const short8 qf0 = *(const short8*)qrow;
  const short8 qf1 = *(const short8*)(qrow + 32);

  float mrun[4], lrun[4];
  f32x4 o[4] = {};
#pragma unroll
  for (int rr = 0; rr < 4; ++rr) { mrun[rr] = -1e30f; lrun[rr] = 0.0f; }

  for (int t = t0 + wv; t < t1; t += 4) {
    const int kv0 = t << 6;
    f32x4 s4[4];
#pragma unroll
    for (int nf = 0; nf < 4; ++nf) {
      const u16* kp = &ks[(b * LL + kv0 + nf * 16 + r) * HH + 8 * g];
      short8 b0 = *(const short8*)kp;
      short8 b1 = *(const short8*)(kp + 32);
      f32x4 z = {};
      z = __builtin_amdgcn_mfma_f32_16x16x32_bf16(qf0, b0, z, 0, 0, 0);
      z = __builtin_amdgcn_mfma_f32_16x16x32_bf16(qf1, b1, z, 0, 0, 0);
      s4[nf] = z;
    }
    if (kv0 + 63 > q0) {               // diagonal-spanning tile
#pragma unroll
      for (int nf = 0; nf < 4; ++nf)
#pragma unroll
        for (int rr = 0; rr < 4; ++rr)
          if (kv0 + nf * 16 + r > q0 + 4 * g + rr) s4[nf][rr] = -1e30f;
    }
    float pm[4];
#pragma unroll
    for (int rr = 0; rr < 4; ++rr)
      pm[rr] = fmaxf(fmaxf(s4[0][rr], s4[1][rr]), fmaxf(s4[2][rr], s4[3][rr]));
#pragma unroll
    for (int xm = 1; xm <= 8; xm <<= 1)
#pragma unroll
      for (int rr = 0; rr < 4; ++rr)
        pm[rr] = fmaxf(pm[rr], __shfl_xor(pm[rr], xm));
    float nm[4], al[4], rs[4];
#pragma unroll
    for (int rr = 0; rr < 4; ++rr) {
      nm[rr] = fmaxf(mrun[rr], pm[rr]);
      al[rr] = exp2x(mrun[rr] - nm[rr]);
      rs[rr] = 0.0f;
    }
#pragma unroll
    for (int nf = 0; nf < 4; ++nf)
#pragma unroll
      for (int rr = 0; rr < 4; ++rr) {
        float p = exp2x(s4[nf][rr] - nm[rr]);
        s4[nf][rr] = p;
        rs[rr] += p;
      }
#pragma unroll
    for (int xm = 1; xm <= 8; xm <<= 1)
#pragma unroll
      for (int rr = 0; rr < 4; ++rr)
        rs[rr] += __shfl_xor(rs[rr], xm);
#pragma unroll
    for (int rr = 0; rr < 4; ++rr) {
      lrun[rr] = lrun[rr] * al[rr] + rs[rr];
      mrun[rr] = nm[rr];
    }
#pragma unroll
    for (int hf = 0; hf < 4; ++hf)
#pragma unroll
      for (int rr = 0; rr < 4; ++rr)
        o[hf][rr] *= al[rr];
#pragma unroll
    for (int nf = 0; nf < 4; ++nf)
#pragma unroll
      for (int rr = 0; rr < 4; ++rr)
        sm.P[wv][(4 * g + rr) * 72 + nf * 16 + r] = f2bf(s4[nf][rr]);
    short8 pa0 = *(const short8*)&sm.P[wv][r * 72 + 8 * g];
    short8 pa1 = *(const short8*)&sm.P[wv][r * 72 + 32 + 8 * g];
#pragma unroll
    for (int hf = 0; hf < 4; ++hf) {
      const u16* vp = &vsT[(b * HH + hf * 16 + r) * LL + kv0 + 8 * g];
      short8 v0 = *(const short8*)vp;
      short8 v1 = *(const short8*)(vp + 32);
      o[hf] = __builtin_amdgcn_mfma_f32_16x16x32_bf16(pa0, v0, o[hf], 0, 0, 0);
      o[hf] = __builtin_amdgcn_mfma_f32_16x16x32_bf16(pa1, v1, o[hf], 0, 0, 0);
    }
  }

  __syncthreads();                     // all waves done using sm.P
#pragma unroll
  for (int hf = 0; hf < 4; ++hf)
#pragma unroll
    for (int rr = 0; rr < 4; ++rr)
      sm.mg.oM[wv][4 * g + rr][hf * 16 + r] = o[hf][rr];
  if (r == 0) {
#pragma unroll
    for (int rr = 0; rr < 4; ++rr) {
      sm.mg.ml[wv][0][4 * g + rr] = mrun[rr];
      sm.mg.ml[wv][1][4 * g + rr] = lrun[rr];
    }
  }
  __syncthreads();

  {
    const int row = tid >> 4;
    const int hq = (tid & 15) * 4;
    float M = sm.mg.ml[0][0][row];
#pragma unroll
    for (int w = 1; w < 4; ++w) M = fmaxf(M, sm.mg.ml[w][0][row]);
    float L = 0.0f;
    float O0 = 0.0f, O1 = 0.0f, O2 = 0.0f, O3 = 0.0f;
#pragma unroll
    for (int w = 0; w < 4; ++w) {
      float al = exp2x(sm.mg.ml[w][0][row] - M);
      L += sm.mg.ml[w][1][row] * al;
      O0 += sm.mg.oM[w][row][hq + 0] * al;
      O1 += sm.mg.oM[w][row][hq + 1] * al;
      O2 += sm.mg.oM[w][row][hq + 2] * al;
      O3 += sm.mg.oM[w][row][hq + 3] * al;
    }
    if (chunk < 0) {
      const float inv = 1.0f / L;
      float4 res = { O0 * inv, O1 * inv, O2 * inv, O3 * inv };
      *(float4*)&out[(b * LL + q0 + row) * HH + hq] = res;
    } else {
      float* pp = part + (((b << 6) + (qt - 64)) * 2 + chunk) * PART_STRIDE;
      if (hq == 0) { pp[row] = M; pp[16 + row] = L; }
      float4 res = { O0, O1, O2, O3 };
      *(float4*)&pp[32 + row * 64 + hq] = res;
    }
  }
}

// ---------------------------------------------------------------------------
// Kernel 3: merge the 2 kv-chunk partials for q-tiles 64..127.
// ---------------------------------------------------------------------------
__global__ __launch_bounds__(256) void attn_merge(const float* __restrict__ part,
                                                  float* __restrict__ out) {
  const int bi = blockIdx.x;           // [0,512) = b*64 + (qt-64)
  const int b = bi >> 6;
  const int qt = 64 + (bi & 63);
  const float* p0 = part + (bi * 2 + 0) * PART_STRIDE;
  const float* p1 = part + (bi * 2 + 1) * PART_STRIDE;
  const int row = threadIdx.x >> 4;
  const int hq = (threadIdx.x & 15) * 4;
  const float m0 = p0[row], l0 = p0[16 + row];
  const float m1 = p1[row], l1 = p1[16 + row];
  const float M = fmaxf(m0, m1);
  const float a0 = exp2x(m0 - M), a1 = exp2x(m1 - M);
  const float inv = 1.0f / (l0 * a0 + l1 * a1);
  float4 O0 = *(const float4*)&p0[32 + row * 64 + hq];
  float4 O1 = *(const float4*)&p1[32 + row * 64 + hq];
  float4 res = { (O0.x * a0 + O1.x * a1) * inv, (O0.y * a0 + O1.y * a1) * inv,
                 (O0.z * a0 + O1.z * a1) * inv, (O0.w * a0 + O1.w * a1) * inv };
  *(float4*)&out[(b * LL + qt * 16 + row) * HH + hq] = res;
}

extern "C" void kernel_launch(void* const* d_in, const int* in_sizes, int n_in,
                              void* d_out, int out_size, void* d_ws, size_t ws_size,
                              hipStream_t stream) {
  const float* x  = (const float*)d_in[0];
  const float* Wk = (const float*)d_in[1];
  const float* Wq = (const float*)d_in[2];
  const float* Wv = (const float*)d_in[3];

  u16* qs  = (u16*)d_ws;             // [16384][64] bf16
  u16* ks  = qs + BL * HH;           // [16384][64] bf16
  u16* vsT = ks + BL * HH;           // [8][64][2048] bf16 (V transposed)
  u16* wtp = vsT + BL * HH;          // [384][512] bf16 (W in frag order)
  float* part = (float*)(wtp + 384 * 512);  // [512][2][PART_STRIDE] f32

  wtp_pack<<<96, 256, 0, stream>>>(Wq, Wk, Wv, wtp);
  qkv_proj<<<BL / 64, 512, 0, stream>>>(x, wtp, qs, ks, vsT);
  attn<<<192 * BQ, 256, 0, stream>>>(qs, ks, vsT, (float*)d_out, part);
  attn_merge<<<512, 256, 0, stream>>>(part, (float*)d_out);
}

// Round 8
// 74.063 us; speedup vs baseline: 1.1325x; 1.1325x over previous
//
#include <hip/hip_runtime.h>
#include <hip/hip_bf16.h>

typedef __attribute__((ext_vector_type(8))) short short8;
typedef __attribute__((ext_vector_type(8))) float f32x8;
typedef __attribute__((ext_vector_type(4))) float f32x4;
typedef unsigned short u16;
typedef unsigned int u32;

#define BQ 8
#define LL 2048
#define NN 1024
#define HH 64
#define BL (BQ * LL) /* 16384 */
#define PART_STRIDE 1056  /* floats per attn partial: 16 m + 16 l + 16x64 O */
#define QSCALE 0.0450842213f  /* (1/32) * log2(e): exp2-domain softmax */

static __device__ __forceinline__ u16 f2bf(float f) {
  union { float f; unsigned int u; } cv;
  cv.f = f;
  unsigned int u = cv.u;
  unsigned int rounded = u + 0x7FFFu + ((u >> 16) & 1u);  // RNE
  return (u16)(rounded >> 16);
}

static __device__ __forceinline__ float exp2x(float x) {
  return __builtin_amdgcn_exp2f(x);
}

// pack 8 f32 -> 8 bf16 by truncation (1 v_perm per 2 elements)
static __device__ __forceinline__ short8 pack_bf16(f32x8 v) {
  short8 o;
  u32* op = (u32*)&o;
#pragma unroll
  for (int w = 0; w < 4; ++w) {
    op[w] = __builtin_amdgcn_perm(__float_as_uint(v[2 * w + 1]),
                                  __float_as_uint(v[2 * w]), 0x07060302u);
  }
  return o;
}

// async global -> LDS, 16B per lane; lds dest must be wave-uniform base
static __device__ __forceinline__ void gload_lds16(const u16* g, u16* l) {
  __builtin_amdgcn_global_load_lds(
      (const __attribute__((address_space(1))) unsigned int*)g,
      (__attribute__((address_space(3))) unsigned int*)l, 16, 0, 0);
}

// ---------------------------------------------------------------------------
// Kernel 0: pack W into MFMA B-fragment order (unchanged).
// ---------------------------------------------------------------------------
__global__ __launch_bounds__(256) void wtp_pack(const float* __restrict__ Wq,
                                                const float* __restrict__ Wk,
                                                const float* __restrict__ Wv,
                                                u16* __restrict__ wtp) {
  int gid = blockIdx.x * 256 + threadIdx.x;   // [0, 384*64)
  int f = gid >> 6;
  int l = gid & 63;
  int m = f >> 7;
  int rem = f & 127;
  int nf = rem >> 5;
  int ks = rem & 31;
  int r = l & 15;
  int g = l >> 4;
  const float* src = (m == 0) ? Wq : (m == 1) ? Wk : Wv;
  short8 o;
#pragma unroll
  for (int j = 0; j < 8; ++j)
    o[j] = (short)f2bf(src[(ks * 32 + 8 * g + j) * HH + nf * 16 + r]);
  *(short8*)&wtp[f * 512 + l * 8] = o;
}

// ---------------------------------------------------------------------------
// Kernel 1: qkv projection, LDS-staged GEMM (unchanged).
// ---------------------------------------------------------------------------
__global__ __launch_bounds__(512, 4) void qkv_proj(const float* __restrict__ x,
                                                   const u16* __restrict__ wtp,
                                                   u16* __restrict__ qs,
                                                   u16* __restrict__ ks_,
                                                   u16* __restrict__ vsT) {
  __shared__ u16 xs[2][64 * 72];     // x tile, row stride 72
  __shared__ u16 ws[2][24 * 512];    // W frags: c = F*2 + ks, frag-linear

  const int row0 = blockIdx.x * 64;
  const int tid = threadIdx.x;
  const int wv = tid >> 6;
  const int lane = tid & 63;
  const int r = lane & 15;
  const int g = lane >> 4;
  const int ms = wv >> 2;            // 32-row half
  const int fq = wv & 3;             // 3-F quarter

  const int srow = tid >> 3;         // 0..63
  const int scol = (tid & 7) * 8;    // 0..56
  const float* xsrc = x + (row0 + srow) * NN + scol;

  f32x4 acc[2][3] = {};

  {
    f32x8 xv = *(const f32x8*)xsrc;
    *(short8*)&xs[0][srow * 72 + scol] = pack_bf16(xv);
#pragma unroll
    for (int j = 0; j < 3; ++j) {
      int c = wv * 3 + j;
      int F = c >> 1, ks = c & 1;
      int gf = F * 32 + ks;
      gload_lds16(wtp + gf * 512 + lane * 8, &ws[0][c * 512]);
    }
  }
  __syncthreads();

  int cur = 0;
  for (int kc = 0; kc < 16; ++kc) {
    f32x8 xnv;
    if (kc < 15) {
      xnv = *(const f32x8*)(xsrc + (kc + 1) * 64);
#pragma unroll
      for (int j = 0; j < 3; ++j) {
        int c = wv * 3 + j;
        int F = c >> 1, ks = c & 1;
        int gf = F * 32 + (kc + 1) * 2 + ks;
        gload_lds16(wtp + gf * 512 + lane * 8, &ws[cur ^ 1][c * 512]);
      }
    }
#pragma unroll
    for (int ks = 0; ks < 2; ++ks) {
      short8 a[2];
#pragma unroll
      for (int mf = 0; mf < 2; ++mf)
        a[mf] = *(const short8*)&xs[cur][(ms * 32 + mf * 16 + r) * 72 + ks * 32 + 8 * g];
#pragma unroll
      for (int i = 0; i < 3; ++i) {
        int c = (fq * 3 + i) * 2 + ks;
        short8 bfr = *(const short8*)&ws[cur][c * 512 + lane * 8];
#pragma unroll
        for (int mf = 0; mf < 2; ++mf)
          acc[mf][i] = __builtin_amdgcn_mfma_f32_16x16x32_bf16(a[mf], bfr, acc[mf][i], 0, 0, 0);
      }
    }
    if (kc < 15)
      *(short8*)&xs[cur ^ 1][srow * 72 + scol] = pack_bf16(xnv);
    __syncthreads();
    cur ^= 1;
  }

  const int b = row0 >> 11;
  const int kvloc = row0 & (LL - 1);
  u16* vt = xs[0];
#pragma unroll
  for (int mf = 0; mf < 2; ++mf) {
#pragma unroll
    for (int i = 0; i < 3; ++i) {
      const int F = fq * 3 + i, m = F >> 2, nf = F & 3;
      const int rowb = row0 + ms * 32 + mf * 16;
      if (m == 0) {
#pragma unroll
        for (int rr = 0; rr < 4; ++rr)
          qs[(rowb + 4 * g + rr) * HH + nf * 16 + r] = f2bf(acc[mf][i][rr] * QSCALE);
      } else if (m == 1) {
#pragma unroll
        for (int rr = 0; rr < 4; ++rr)
          ks_[(rowb + 4 * g + rr) * HH + nf * 16 + r] = f2bf(acc[mf][i][rr]);
      } else {
#pragma unroll
        for (int rr = 0; rr < 4; ++rr)
          vt[(nf * 16 + r) * 72 + ms * 32 + mf * 16 + 4 * g + rr] = f2bf(acc[mf][i][rr]);
      }
    }
  }
  __syncthreads();
  if (tid < 256) {
    const int h = tid >> 2;
    const int seg = (tid & 3) * 16;
    const u16* s = &vt[h * 72 + seg];
    u16* d = &vsT[(b * HH + h) * LL + kvloc + seg];
    *(short8*)d = *(short8*)s;
    *(short8*)(d + 8) = *(short8*)(s + 8);
  }
}

// ---------------------------------------------------------------------------
// Kernel 2: causal flash attention with 2-way kv-split for long q-tiles.
// Same structure as r7 but launch_bounds (256,4): 128-reg budget, no spills.
// ---------------------------------------------------------------------------
__global__ __launch_bounds__(256, 4) void attn(const u16* __restrict__ qs,
                                               const u16* __restrict__ ks,
                                               const u16* __restrict__ vsT,
                                               float* __restrict__ out,
                                               float* __restrict__ part) {
  __shared__ union {
    u16 P[4][16 * 72];
    struct { float oM[4][16][64]; float ml[4][2][16]; } mg;
  } sm;

  const int bi = blockIdx.x;
  const int cid = bi >> 3;
  const int b = bi & 7;                // batch -> XCD pinning
  int qt, t0, t1, chunk;
  if (cid < 64) {
    qt = 64 + cid; chunk = 0; t0 = 0; t1 = 16;
  } else {
    qt = 191 - cid;
    const int nt = (qt + 4) >> 2;      // ceil((qt+1)/4)
    if (cid < 128) { chunk = 1; t0 = 16; t1 = nt; }
    else           { chunk = -1; t0 = 0; t1 = nt; }
  }
  const int q0 = qt * 16;

  const int tid = threadIdx.x;
  const int lane = tid & 63;
  const int wv = tid >> 6;
  const int r = lane & 15;
  const int g = lane >> 4;

  const u16* qrow = &qs[(b * LL + q0 + r) * HH + 8 * g];
  const short8 qf0 = *(const short8*)qrow;
  const short8 qf1 = *(const short8*)(qrow + 32);

  float mrun[4], lrun[4];
  f32x4 o[4] = {};
#pragma unroll
  for (int rr = 0; rr < 4; ++rr) { mrun[rr] = -1e30f; lrun[rr] = 0.0f; }

  for (int t = t0 + wv; t < t1; t += 4) {
    const int kv0 = t << 6;
    f32x4 s4[4];
#pragma unroll
    for (int nf = 0; nf < 4; ++nf) {
      const u16* kp = &ks[(b * LL + kv0 + nf * 16 + r) * HH + 8 * g];
      short8 b0 = *(const short8*)kp;
      short8 b1 = *(const short8*)(kp + 32);
      f32x4 z = {};
      z = __builtin_amdgcn_mfma_f32_16x16x32_bf16(qf0, b0, z, 0, 0, 0);
      z = __builtin_amdgcn_mfma_f32_16x16x32_bf16(qf1, b1, z, 0, 0, 0);
      s4[nf] = z;
    }
    if (kv0 + 63 > q0) {               // diagonal-spanning tile
#pragma unroll
      for (int nf = 0; nf < 4; ++nf)
#pragma unroll
        for (int rr = 0; rr < 4; ++rr)
          if (kv0 + nf * 16 + r > q0 + 4 * g + rr) s4[nf][rr] = -1e30f;
    }
    float pm[4];
#pragma unroll
    for (int rr = 0; rr < 4; ++rr)
      pm[rr] = fmaxf(fmaxf(s4[0][rr], s4[1][rr]), fmaxf(s4[2][rr], s4[3][rr]));
#pragma unroll
    for (int xm = 1; xm <= 8; xm <<= 1)
#pragma unroll
      for (int rr = 0; rr < 4; ++rr)
        pm[rr] = fmaxf(pm[rr], __shfl_xor(pm[rr], xm));
    float nm[4], al[4], rs[4];
#pragma unroll
    for (int rr = 0; rr < 4; ++rr) {
      nm[rr] = fmaxf(mrun[rr], pm[rr]);
      al[rr] = exp2x(mrun[rr] - nm[rr]);
      rs[rr] = 0.0f;
    }
#pragma unroll
    for (int nf = 0; nf < 4; ++nf)
#pragma unroll
      for (int rr = 0; rr < 4; ++rr) {
        float p = exp2x(s4[nf][rr] - nm[rr]);
        s4[nf][rr] = p;
        rs[rr] += p;
      }
#pragma unroll
    for (int xm = 1; xm <= 8; xm <<= 1)
#pragma unroll
      for (int rr = 0; rr < 4; ++rr)
        rs[rr] += __shfl_xor(rs[rr], xm);
#pragma unroll
    for (int rr = 0; rr < 4; ++rr) {
      lrun[rr] = lrun[rr] * al[rr] + rs[rr];
      mrun[rr] = nm[rr];
    }
#pragma unroll
    for (int hf = 0; hf < 4; ++hf)
#pragma unroll
      for (int rr = 0; rr < 4; ++rr)
        o[hf][rr] *= al[rr];
#pragma unroll
    for (int nf = 0; nf < 4; ++nf)
#pragma unroll
      for (int rr = 0; rr < 4; ++rr)
        sm.P[wv][(4 * g + rr) * 72 + nf * 16 + r] = f2bf(s4[nf][rr]);
    short8 pa0 = *(const short8*)&sm.P[wv][r * 72 + 8 * g];
    short8 pa1 = *(const short8*)&sm.P[wv][r * 72 + 32 + 8 * g];
#pragma unroll
    for (int hf = 0; hf < 4; ++hf) {
      const u16* vp = &vsT[(b * HH + hf * 16 + r) * LL + kv0 + 8 * g];
      short8 v0 = *(const short8*)vp;
      short8 v1 = *(const short8*)(vp + 32);
      o[hf] = __builtin_amdgcn_mfma_f32_16x16x32_bf16(pa0, v0, o[hf], 0, 0, 0);
      o[hf] = __builtin_amdgcn_mfma_f32_16x16x32_bf16(pa1, v1, o[hf], 0, 0, 0);
    }
  }

  __syncthreads();                     // all waves done using sm.P
#pragma unroll
  for (int hf = 0; hf < 4; ++hf)
#pragma unroll
    for (int rr = 0; rr < 4; ++rr)
      sm.mg.oM[wv][4 * g + rr][hf * 16 + r] = o[hf][rr];
  if (r == 0) {
#pragma unroll
    for (int rr = 0; rr < 4; ++rr) {
      sm.mg.ml[wv][0][4 * g + rr] = mrun[rr];
      sm.mg.ml[wv][1][4 * g + rr] = lrun[rr];
    }
  }
  __syncthreads();

  {
    const int row = tid >> 4;
    const int hq = (tid & 15) * 4;
    float M = sm.mg.ml[0][0][row];
#pragma unroll
    for (int w = 1; w < 4; ++w) M = fmaxf(M, sm.mg.ml[w][0][row]);
    float L = 0.0f;
    float O0 = 0.0f, O1 = 0.0f, O2 = 0.0f, O3 = 0.0f;
#pragma unroll
    for (int w = 0; w < 4; ++w) {
      float al = exp2x(sm.mg.ml[w][0][row] - M);
      L += sm.mg.ml[w][1][row] * al;
      O0 += sm.mg.oM[w][row][hq + 0] * al;
      O1 += sm.mg.oM[w][row][hq + 1] * al;
      O2 += sm.mg.oM[w][row][hq + 2] * al;
      O3 += sm.mg.oM[w][row][hq + 3] * al;
    }
    if (chunk < 0) {
      const float inv = 1.0f / L;
      float4 res = { O0 * inv, O1 * inv, O2 * inv, O3 * inv };
      *(float4*)&out[(b * LL + q0 + row) * HH + hq] = res;
    } else {
      float* pp = part + (((b << 6) + (qt - 64)) * 2 + chunk) * PART_STRIDE;
      if (hq == 0) { pp[row] = M; pp[16 + row] = L; }
      float4 res = { O0, O1, O2, O3 };
      *(float4*)&pp[32 + row * 64 + hq] = res;
    }
  }
}

// ---------------------------------------------------------------------------
// Kernel 3: merge the 2 kv-chunk partials for q-tiles 64..127.
// ---------------------------------------------------------------------------
__global__ __launch_bounds__(256) void attn_merge(const float* __restrict__ part,
                                                  float* __restrict__ out) {
  const int bi = blockIdx.x;           // [0,512) = b*64 + (qt-64)
  const int b = bi >> 6;
  const int qt = 64 + (bi & 63);
  const float* p0 = part + (bi * 2 + 0) * PART_STRIDE;
  const float* p1 = part + (bi * 2 + 1) * PART_STRIDE;
  const int row = threadIdx.x >> 4;
  const int hq = (threadIdx.x & 15) * 4;
  const float m0 = p0[row], l0 = p0[16 + row];
  const float m1 = p1[row], l1 = p1[16 + row];
  const float M = fmaxf(m0, m1);
  const float a0 = exp2x(m0 - M), a1 = exp2x(m1 - M);
  const float inv = 1.0f / (l0 * a0 + l1 * a1);
  float4 O0 = *(const float4*)&p0[32 + row * 64 + hq];
  float4 O1 = *(const float4*)&p1[32 + row * 64 + hq];
  float4 res = { (O0.x * a0 + O1.x * a1) * inv, (O0.y * a0 + O1.y * a1) * inv,
                 (O0.z * a0 + O1.z * a1) * inv, (O0.w * a0 + O1.w * a1) * inv };
  *(float4*)&out[(b * LL + qt * 16 + row) * HH + hq] = res;
}

extern "C" void kernel_launch(void* const* d_in, const int* in_sizes, int n_in,
                              void* d_out, int out_size, void* d_ws, size_t ws_size,
                              hipStream_t stream) {
  const float* x  = (const float*)d_in[0];
  const float* Wk = (const float*)d_in[1];
  const float* Wq = (const float*)d_in[2];
  const float* Wv = (const float*)d_in[3];

  u16* qs  = (u16*)d_ws;             // [16384][64] bf16
  u16* ks  = qs + BL * HH;           // [16384][64] bf16
  u16* vsT = ks + BL * HH;           // [8][64][2048] bf16 (V transposed)
  u16* wtp = vsT + BL * HH;          // [384][512] bf16 (W in frag order)
  float* part = (float*)(wtp + 384 * 512);  // [512][2][PART_STRIDE] f32

  wtp_pack<<<96, 256, 0, stream>>>(Wq, Wk, Wv, wtp);
  qkv_proj<<<BL / 64, 512, 0, stream>>>(x, wtp, qs, ks, vsT);
  attn<<<192 * BQ, 256, 0, stream>>>(qs, ks, vsT, (float*)d_out, part);
  attn_merge<<<512, 256, 0, stream>>>(part, (float*)d_out);
}

// Round 9
// 69.582 us; speedup vs baseline: 1.2054x; 1.0644x over previous
//
#include <hip/hip_runtime.h>
#include <hip/hip_bf16.h>

typedef __attribute__((ext_vector_type(8))) short short8;
typedef __attribute__((ext_vector_type(8))) float f32x8;
typedef __attribute__((ext_vector_type(4))) float f32x4;
typedef unsigned short u16;
typedef unsigned int u32;

#define BQ 8
#define LL 2048
#define NN 1024
#define HH 64
#define BL (BQ * LL) /* 16384 */
#define PART_STRIDE 1056  /* floats per attn partial: 16 m + 16 l + 16x64 O */
#define QSCALE 0.0450842213f  /* (1/32) * log2(e): exp2-domain softmax */

static __device__ __forceinline__ u16 f2bf(float f) {
  union { float f; unsigned int u; } cv;
  cv.f = f;
  unsigned int u = cv.u;
  unsigned int rounded = u + 0x7FFFu + ((u >> 16) & 1u);  // RNE
  return (u16)(rounded >> 16);
}

static __device__ __forceinline__ float exp2x(float x) {
  return __builtin_amdgcn_exp2f(x);
}

// pack two f32 -> one dword of 2 bf16 (lo = first arg)
static __device__ __forceinline__ u32 cvtpk(float lo, float hi) {
  u32 d;
  asm("v_cvt_pk_bf16_f32 %0, %1, %2" : "=v"(d) : "v"(lo), "v"(hi));
  return d;
}

// pack 8 f32 -> 8 bf16 by truncation (1 v_perm per 2 elements)
static __device__ __forceinline__ short8 pack_bf16(f32x8 v) {
  short8 o;
  u32* op = (u32*)&o;
#pragma unroll
  for (int w = 0; w < 4; ++w) {
    op[w] = __builtin_amdgcn_perm(__float_as_uint(v[2 * w + 1]),
                                  __float_as_uint(v[2 * w]), 0x07060302u);
  }
  return o;
}

// async global -> LDS, 16B per lane; lds dest must be wave-uniform base
static __device__ __forceinline__ void gload_lds16(const u16* g, u16* l) {
  __builtin_amdgcn_global_load_lds(
      (const __attribute__((address_space(1))) unsigned int*)g,
      (__attribute__((address_space(3))) unsigned int*)l, 16, 0, 0);
}

// ---------------------------------------------------------------------------
// Kernel 0: pack W into MFMA B-fragment order (unchanged).
// ---------------------------------------------------------------------------
__global__ __launch_bounds__(256) void wtp_pack(const float* __restrict__ Wq,
                                                const float* __restrict__ Wk,
                                                const float* __restrict__ Wv,
                                                u16* __restrict__ wtp) {
  int gid = blockIdx.x * 256 + threadIdx.x;   // [0, 384*64)
  int f = gid >> 6;
  int l = gid & 63;
  int m = f >> 7;
  int rem = f & 127;
  int nf = rem >> 5;
  int ks = rem & 31;
  int r = l & 15;
  int g = l >> 4;
  const float* src = (m == 0) ? Wq : (m == 1) ? Wk : Wv;
  short8 o;
#pragma unroll
  for (int j = 0; j < 8; ++j)
    o[j] = (short)f2bf(src[(ks * 32 + 8 * g + j) * HH + nf * 16 + r]);
  *(short8*)&wtp[f * 512 + l * 8] = o;
}

// ---------------------------------------------------------------------------
// Kernel 1: qkv projection, LDS-staged GEMM (unchanged).
// ---------------------------------------------------------------------------
__global__ __launch_bounds__(512, 4) void qkv_proj(const float* __restrict__ x,
                                                   const u16* __restrict__ wtp,
                                                   u16* __restrict__ qs,
                                                   u16* __restrict__ ks_,
                                                   u16* __restrict__ vsT) {
  __shared__ u16 xs[2][64 * 72];     // x tile, row stride 72
  __shared__ u16 ws[2][24 * 512];    // W frags: c = F*2 + ks, frag-linear

  const int row0 = blockIdx.x * 64;
  const int tid = threadIdx.x;
  const int wv = tid >> 6;
  const int lane = tid & 63;
  const int r = lane & 15;
  const int g = lane >> 4;
  const int ms = wv >> 2;            // 32-row half
  const int fq = wv & 3;             // 3-F quarter

  const int srow = tid >> 3;         // 0..63
  const int scol = (tid & 7) * 8;    // 0..56
  const float* xsrc = x + (row0 + srow) * NN + scol;

  f32x4 acc[2][3] = {};

  {
    f32x8 xv = *(const f32x8*)xsrc;
    *(short8*)&xs[0][srow * 72 + scol] = pack_bf16(xv);
#pragma unroll
    for (int j = 0; j < 3; ++j) {
      int c = wv * 3 + j;
      int F = c >> 1, ks = c & 1;
      int gf = F * 32 + ks;
      gload_lds16(wtp + gf * 512 + lane * 8, &ws[0][c * 512]);
    }
  }
  __syncthreads();

  int cur = 0;
  for (int kc = 0; kc < 16; ++kc) {
    f32x8 xnv;
    if (kc < 15) {
      xnv = *(const f32x8*)(xsrc + (kc + 1) * 64);
#pragma unroll
      for (int j = 0; j < 3; ++j) {
        int c = wv * 3 + j;
        int F = c >> 1, ks = c & 1;
        int gf = F * 32 + (kc + 1) * 2 + ks;
        gload_lds16(wtp + gf * 512 + lane * 8, &ws[cur ^ 1][c * 512]);
      }
    }
#pragma unroll
    for (int ks = 0; ks < 2; ++ks) {
      short8 a[2];
#pragma unroll
      for (int mf = 0; mf < 2; ++mf)
        a[mf] = *(const short8*)&xs[cur][(ms * 32 + mf * 16 + r) * 72 + ks * 32 + 8 * g];
#pragma unroll
      for (int i = 0; i < 3; ++i) {
        int c = (fq * 3 + i) * 2 + ks;
        short8 bfr = *(const short8*)&ws[cur][c * 512 + lane * 8];
#pragma unroll
        for (int mf = 0; mf < 2; ++mf)
          acc[mf][i] = __builtin_amdgcn_mfma_f32_16x16x32_bf16(a[mf], bfr, acc[mf][i], 0, 0, 0);
      }
    }
    if (kc < 15)
      *(short8*)&xs[cur ^ 1][srow * 72 + scol] = pack_bf16(xnv);
    __syncthreads();
    cur ^= 1;
  }

  const int b = row0 >> 11;
  const int kvloc = row0 & (LL - 1);
  u16* vt = xs[0];
#pragma unroll
  for (int mf = 0; mf < 2; ++mf) {
#pragma unroll
    for (int i = 0; i < 3; ++i) {
      const int F = fq * 3 + i, m = F >> 2, nf = F & 3;
      const int rowb = row0 + ms * 32 + mf * 16;
      if (m == 0) {
#pragma unroll
        for (int rr = 0; rr < 4; ++rr)
          qs[(rowb + 4 * g + rr) * HH + nf * 16 + r] = f2bf(acc[mf][i][rr] * QSCALE);
      } else if (m == 1) {
#pragma unroll
        for (int rr = 0; rr < 4; ++rr)
          ks_[(rowb + 4 * g + rr) * HH + nf * 16 + r] = f2bf(acc[mf][i][rr]);
      } else {
#pragma unroll
        for (int rr = 0; rr < 4; ++rr)
          vt[(nf * 16 + r) * 72 + ms * 32 + mf * 16 + 4 * g + rr] = f2bf(acc[mf][i][rr]);
      }
    }
  }
  __syncthreads();
  if (tid < 256) {
    const int h = tid >> 2;
    const int seg = (tid & 3) * 16;
    const u16* s = &vt[h * 72 + seg];
    u16* d = &vsT[(b * HH + h) * LL + kvloc + seg];
    *(short8*)d = *(short8*)s;
    *(short8*)(d + 8) = *(short8*)(s + 8);
  }
}

// ---------------------------------------------------------------------------
// Kernel 2: causal flash attention, swapped-QK^T in-register softmax.
// S^T = mfma(K, Q): lane (r,g) holds S[q0+r][kv0+16nf+4g+rr] -> row
// reductions are 15 in-lane ops + 2 shfl_xor. P packed via v_cvt_pk_bf16_f32,
// 4 ds_write_b64 + 2 ds_read_b128 rebuild the PV A-fragment.
// kv-split grid identical to r8.
// ---------------------------------------------------------------------------
__global__ __launch_bounds__(256, 4) void attn(const u16* __restrict__ qs,
                                               const u16* __restrict__ ks,
                                               const u16* __restrict__ vsT,
                                               float* __restrict__ out,
                                               float* __restrict__ part) {
  __shared__ union {
    u32 P[4][16 * 36];                 // per-wave P dwords, row stride 36
    struct { float oM[4][16][64]; float ml[4][2][16]; } mg;
  } sm;

  const int bi = blockIdx.x;
  const int cid = bi >> 3;
  const int b = bi & 7;                // batch -> XCD pinning
  int qt, t0, t1, chunk;
  if (cid < 64) {
    qt = 64 + cid; chunk = 0; t0 = 0; t1 = 16;
  } else {
    qt = 191 - cid;
    const int nt = (qt + 4) >> 2;      // ceil((qt+1)/4)
    if (cid < 128) { chunk = 1; t0 = 16; t1 = nt; }
    else           { chunk = -1; t0 = 0; t1 = nt; }
  }
  const int q0 = qt * 16;

  const int tid = threadIdx.x;
  const int lane = tid & 63;
  const int wv = tid >> 6;
  const int r = lane & 15;
  const int g = lane >> 4;

  const u16* qrow = &qs[(b * LL + q0 + r) * HH + 8 * g];
  const short8 qf0 = *(const short8*)qrow;   // B-frag: col=r (q-row), k=dim
  const short8 qf1 = *(const short8*)(qrow + 32);

  float mrun = -1e30f, lrun = 0.0f;    // softmax state for q-row r
  f32x4 o[4] = {};                     // O in D layout: row(q)=4g+rr, col(h)=r

  for (int t = t0 + wv; t < t1; t += 4) {
    const int kv0 = t << 6;
    // ---- S^T = K·Q^T: A-frag = K rows (same loads as B-frag before)
    f32x4 s4[4];
#pragma unroll
    for (int nf = 0; nf < 4; ++nf) {
      const u16* kp = &ks[(b * LL + kv0 + nf * 16 + r) * HH + 8 * g];
      short8 k0 = *(const short8*)kp;
      short8 k1 = *(const short8*)(kp + 32);
      f32x4 z = {};
      __builtin_amdgcn_s_setprio(1);
      z = __builtin_amdgcn_mfma_f32_16x16x32_bf16(k0, qf0, z, 0, 0, 0);
      z = __builtin_amdgcn_mfma_f32_16x16x32_bf16(k1, qf1, z, 0, 0, 0);
      __builtin_amdgcn_s_setprio(0);
      s4[nf] = z;                      // s4[nf][rr] = S[q0+r][kv0+16nf+4g+rr]
    }
    if (kv0 + 63 > q0) {               // diagonal-spanning tile: causal mask
#pragma unroll
      for (int nf = 0; nf < 4; ++nf)
#pragma unroll
        for (int rr = 0; rr < 4; ++rr)
          if (kv0 + nf * 16 + 4 * g + rr > q0 + r) s4[nf][rr] = -1e30f;
    }
    // ---- row max for q-row r: in-lane over 16 + 2 cross-g shuffles
    float pm = s4[0][0];
#pragma unroll
    for (int nf = 0; nf < 4; ++nf)
#pragma unroll
      for (int rr = 0; rr < 4; ++rr) pm = fmaxf(pm, s4[nf][rr]);
    pm = fmaxf(pm, __shfl_xor(pm, 16));
    pm = fmaxf(pm, __shfl_xor(pm, 32));
    const float nm = fmaxf(mrun, pm);
    const float al = exp2x(mrun - nm);
    // ---- p = exp2(s - nm), row sum
    float rs = 0.0f;
#pragma unroll
    for (int nf = 0; nf < 4; ++nf)
#pragma unroll
      for (int rr = 0; rr < 4; ++rr) {
        float p = exp2x(s4[nf][rr] - nm);
        s4[nf][rr] = p;
        rs += p;
      }
    rs += __shfl_xor(rs, 16);
    rs += __shfl_xor(rs, 32);
    lrun = lrun * al + rs;
    mrun = nm;
    // ---- rescale O: need al for q-row 4g+rr (this lane's D rows)
    float alD[4];
#pragma unroll
    for (int rr = 0; rr < 4; ++rr) alD[rr] = __shfl(al, 4 * g + rr);
#pragma unroll
    for (int hf = 0; hf < 4; ++hf)
#pragma unroll
      for (int rr = 0; rr < 4; ++rr) o[hf][rr] *= alD[rr];
    // ---- P -> bf16 dwords -> LDS -> A-frag  (row q=r, dword w = kv/2)
    u32* pd = &sm.P[wv][r * 36];
#pragma unroll
    for (int nf = 0; nf < 4; ++nf) {
      u32 d0 = cvtpk(s4[nf][0], s4[nf][1]);   // kv 16nf+4g+0,1
      u32 d1 = cvtpk(s4[nf][2], s4[nf][3]);   // kv 16nf+4g+2,3
      uint2 dd = { d0, d1 };
      *(uint2*)&pd[8 * nf + 2 * g] = dd;      // w = 8nf+2g, 8nf+2g+1
    }
    short8 pa0 = *(const short8*)&pd[4 * g];        // kv 8g..8g+7
    short8 pa1 = *(const short8*)&pd[16 + 4 * g];   // kv 32+8g..+7
    // ---- O += P @ V  (V^T B-frags from global/L2)
    __builtin_amdgcn_s_setprio(1);
#pragma unroll
    for (int hf = 0; hf < 4; ++hf) {
      const u16* vp = &vsT[(b * HH + hf * 16 + r) * LL + kv0 + 8 * g];
      short8 v0 = *(const short8*)vp;
      short8 v1 = *(const short8*)(vp + 32);
      o[hf] = __builtin_amdgcn_mfma_f32_16x16x32_bf16(pa0, v0, o[hf], 0, 0, 0);
      o[hf] = __builtin_amdgcn_mfma_f32_16x16x32_bf16(pa1, v1, o[hf], 0, 0, 0);
    }
    __builtin_amdgcn_s_setprio(0);
  }

  __syncthreads();                     // all waves done using sm.P
#pragma unroll
  for (int hf = 0; hf < 4; ++hf)
#pragma unroll
    for (int rr = 0; rr < 4; ++rr)
      sm.mg.oM[wv][4 * g + rr][hf * 16 + r] = o[hf][rr];
  if (g == 0) {                        // state lives at q-row = r
    sm.mg.ml[wv][0][r] = mrun;
    sm.mg.ml[wv][1][r] = lrun;
  }
  __syncthreads();

  {
    const int row = tid >> 4;
    const int hq = (tid & 15) * 4;
    float M = sm.mg.ml[0][0][row];
#pragma unroll
    for (int w = 1; w < 4; ++w) M = fmaxf(M, sm.mg.ml[w][0][row]);
    float L = 0.0f;
    float O0 = 0.0f, O1 = 0.0f, O2 = 0.0f, O3 = 0.0f;
#pragma unroll
    for (int w = 0; w < 4; ++w) {
      float al = exp2x(sm.mg.ml[w][0][row] - M);
      L += sm.mg.ml[w][1][row] * al;
      O0 += sm.mg.oM[w][row][hq + 0] * al;
      O1 += sm.mg.oM[w][row][hq + 1] * al;
      O2 += sm.mg.oM[w][row][hq + 2] * al;
      O3 += sm.mg.oM[w][row][hq + 3] * al;
    }
    if (chunk < 0) {
      const float inv = 1.0f / L;
      float4 res = { O0 * inv, O1 * inv, O2 * inv, O3 * inv };
      *(float4*)&out[(b * LL + q0 + row) * HH + hq] = res;
    } else {
      float* pp = part + (((b << 6) + (qt - 64)) * 2 + chunk) * PART_STRIDE;
      if (hq == 0) { pp[row] = M; pp[16 + row] = L; }
      float4 res = { O0, O1, O2, O3 };
      *(float4*)&pp[32 + row * 64 + hq] = res;
    }
  }
}

// ---------------------------------------------------------------------------
// Kernel 3: merge the 2 kv-chunk partials for q-tiles 64..127 (unchanged).
// ---------------------------------------------------------------------------
__global__ __launch_bounds__(256) void attn_merge(const float* __restrict__ part,
                                                  float* __restrict__ out) {
  const int bi = blockIdx.x;           // [0,512) = b*64 + (qt-64)
  const int b = bi >> 6;
  const int qt = 64 + (bi & 63);
  const float* p0 = part + (bi * 2 + 0) * PART_STRIDE;
  const float* p1 = part + (bi * 2 + 1) * PART_STRIDE;
  const int row = threadIdx.x >> 4;
  const int hq = (threadIdx.x & 15) * 4;
  const float m0 = p0[row], l0 = p0[16 + row];
  const float m1 = p1[row], l1 = p1[16 + row];
  const float M = fmaxf(m0, m1);
  const float a0 = exp2x(m0 - M), a1 = exp2x(m1 - M);
  const float inv = 1.0f / (l0 * a0 + l1 * a1);
  float4 O0 = *(const float4*)&p0[32 + row * 64 + hq];
  float4 O1 = *(const float4*)&p1[32 + row * 64 + hq];
  float4 res = { (O0.x * a0 + O1.x * a1) * inv, (O0.y * a0 + O1.y * a1) * inv,
                 (O0.z * a0 + O1.z * a1) * inv, (O0.w * a0 + O1.w * a1) * inv };
  *(float4*)&out[(b * LL + qt * 16 + row) * HH + hq] = res;
}

extern "C" void kernel_launch(void* const* d_in, const int* in_sizes, int n_in,
                              void* d_out, int out_size, void* d_ws, size_t ws_size,
                              hipStream_t stream) {
  const float* x  = (const float*)d_in[0];
  const float* Wk = (const float*)d_in[1];
  const float* Wq = (const float*)d_in[2];
  const float* Wv = (const float*)d_in[3];

  u16* qs  = (u16*)d_ws;             // [16384][64] bf16
  u16* ks  = qs + BL * HH;           // [16384][64] bf16
  u16* vsT = ks + BL * HH;           // [8][64][2048] bf16 (V transposed)
  u16* wtp = vsT + BL * HH;          // [384][512] bf16 (W in frag order)
  float* part = (float*)(wtp + 384 * 512);  // [512][2][PART_STRIDE] f32

  wtp_pack<<<96, 256, 0, stream>>>(Wq, Wk, Wv, wtp);
  qkv_proj<<<BL / 64, 512, 0, stream>>>(x, wtp, qs, ks, vsT);
  attn<<<192 * BQ, 256, 0, stream>>>(qs, ks, vsT, (float*)d_out, part);
  attn_merge<<<512, 256, 0, stream>>>(part, (float*)d_out);
}

// Round 10
// 58.087 us; speedup vs baseline: 1.4439x; 1.1979x over previous
//
#include <hip/hip_runtime.h>
#include <hip/hip_bf16.h>

typedef __attribute__((ext_vector_type(8))) short short8;
typedef __attribute__((ext_vector_type(8))) float f32x8;
typedef __attribute__((ext_vector_type(4))) float f32x4;
typedef __attribute__((ext_vector_type(16))) float f32x16;
typedef __attribute__((ext_vector_type(4))) unsigned int u32x4;
typedef unsigned short u16;
typedef unsigned int u32;

#define BQ 8
#define LL 2048
#define NN 1024
#define HH 64
#define BL (BQ * LL) /* 16384 */
#define PART32 2112   /* floats per attn partial: 32 m + 32 l + 32x64 O */
#define QSCALE 0.0450842213f  /* (1/32) * log2(e): exp2-domain softmax */

static __device__ __forceinline__ u16 f2bf(float f) {
  union { float f; unsigned int u; } cv;
  cv.f = f;
  unsigned int u = cv.u;
  unsigned int rounded = u + 0x7FFFu + ((u >> 16) & 1u);  // RNE
  return (u16)(rounded >> 16);
}

static __device__ __forceinline__ float exp2x(float x) {
  return __builtin_amdgcn_exp2f(x);
}

// pack two f32 -> one dword of 2 bf16 (lo = first arg)
static __device__ __forceinline__ u32 cvtpk(float lo, float hi) {
  u32 d;
  asm("v_cvt_pk_bf16_f32 %0, %1, %2" : "=v"(d) : "v"(lo), "v"(hi));
  return d;
}

// pack 8 f32 -> 8 bf16 by truncation (1 v_perm per 2 elements)
static __device__ __forceinline__ short8 pack_bf16(f32x8 v) {
  short8 o;
  u32* op = (u32*)&o;
#pragma unroll
  for (int w = 0; w < 4; ++w) {
    op[w] = __builtin_amdgcn_perm(__float_as_uint(v[2 * w + 1]),
                                  __float_as_uint(v[2 * w]), 0x07060302u);
  }
  return o;
}

// async global -> LDS, 16B per lane; lds dest must be wave-uniform base
static __device__ __forceinline__ void gload_lds16(const u16* g, u16* l) {
  __builtin_amdgcn_global_load_lds(
      (const __attribute__((address_space(1))) unsigned int*)g,
      (__attribute__((address_space(3))) unsigned int*)l, 16, 0, 0);
}

static __device__ __forceinline__ f32x16 mfma32(short8 a, short8 b, f32x16 c) {
  return __builtin_amdgcn_mfma_f32_32x32x16_bf16(a, b, c, 0, 0, 0);
}

// ---------------------------------------------------------------------------
// Kernel 0: pack W into MFMA B-fragment order (unchanged).
// ---------------------------------------------------------------------------
__global__ __launch_bounds__(256) void wtp_pack(const float* __restrict__ Wq,
                                                const float* __restrict__ Wk,
                                                const float* __restrict__ Wv,
                                                u16* __restrict__ wtp) {
  int gid = blockIdx.x * 256 + threadIdx.x;   // [0, 384*64)
  int f = gid >> 6;
  int l = gid & 63;
  int m = f >> 7;
  int rem = f & 127;
  int nf = rem >> 5;
  int ks = rem & 31;
  int r = l & 15;
  int g = l >> 4;
  const float* src = (m == 0) ? Wq : (m == 1) ? Wk : Wv;
  short8 o;
#pragma unroll
  for (int j = 0; j < 8; ++j)
    o[j] = (short)f2bf(src[(ks * 32 + 8 * g + j) * HH + nf * 16 + r]);
  *(short8*)&wtp[f * 512 + l * 8] = o;
}

// ---------------------------------------------------------------------------
// Kernel 1: qkv projection, LDS-staged GEMM (unchanged).
// ---------------------------------------------------------------------------
__global__ __launch_bounds__(512, 4) void qkv_proj(const float* __restrict__ x,
                                                   const u16* __restrict__ wtp,
                                                   u16* __restrict__ qs,
                                                   u16* __restrict__ ks_,
                                                   u16* __restrict__ vsT) {
  __shared__ u16 xs[2][64 * 72];     // x tile, row stride 72
  __shared__ u16 ws[2][24 * 512];    // W frags: c = F*2 + ks, frag-linear

  const int row0 = blockIdx.x * 64;
  const int tid = threadIdx.x;
  const int wv = tid >> 6;
  const int lane = tid & 63;
  const int r = lane & 15;
  const int g = lane >> 4;
  const int ms = wv >> 2;            // 32-row half
  const int fq = wv & 3;             // 3-F quarter

  const int srow = tid >> 3;         // 0..63
  const int scol = (tid & 7) * 8;    // 0..56
  const float* xsrc = x + (row0 + srow) * NN + scol;

  f32x4 acc[2][3] = {};

  {
    f32x8 xv = *(const f32x8*)xsrc;
    *(short8*)&xs[0][srow * 72 + scol] = pack_bf16(xv);
#pragma unroll
    for (int j = 0; j < 3; ++j) {
      int c = wv * 3 + j;
      int F = c >> 1, ks = c & 1;
      int gf = F * 32 + ks;
      gload_lds16(wtp + gf * 512 + lane * 8, &ws[0][c * 512]);
    }
  }
  __syncthreads();

  int cur = 0;
  for (int kc = 0; kc < 16; ++kc) {
    f32x8 xnv;
    if (kc < 15) {
      xnv = *(const f32x8*)(xsrc + (kc + 1) * 64);
#pragma unroll
      for (int j = 0; j < 3; ++j) {
        int c = wv * 3 + j;
        int F = c >> 1, ks = c & 1;
        int gf = F * 32 + (kc + 1) * 2 + ks;
        gload_lds16(wtp + gf * 512 + lane * 8, &ws[cur ^ 1][c * 512]);
      }
    }
#pragma unroll
    for (int ks = 0; ks < 2; ++ks) {
      short8 a[2];
#pragma unroll
      for (int mf = 0; mf < 2; ++mf)
        a[mf] = *(const short8*)&xs[cur][(ms * 32 + mf * 16 + r) * 72 + ks * 32 + 8 * g];
#pragma unroll
      for (int i = 0; i < 3; ++i) {
        int c = (fq * 3 + i) * 2 + ks;
        short8 bfr = *(const short8*)&ws[cur][c * 512 + lane * 8];
#pragma unroll
        for (int mf = 0; mf < 2; ++mf)
          acc[mf][i] = __builtin_amdgcn_mfma_f32_16x16x32_bf16(a[mf], bfr, acc[mf][i], 0, 0, 0);
      }
    }
    if (kc < 15)
      *(short8*)&xs[cur ^ 1][srow * 72 + scol] = pack_bf16(xnv);
    __syncthreads();
    cur ^= 1;
  }

  const int b = row0 >> 11;
  const int kvloc = row0 & (LL - 1);
  u16* vt = xs[0];
#pragma unroll
  for (int mf = 0; mf < 2; ++mf) {
#pragma unroll
    for (int i = 0; i < 3; ++i) {
      const int F = fq * 3 + i, m = F >> 2, nf = F & 3;
      const int rowb = row0 + ms * 32 + mf * 16;
      if (m == 0) {
#pragma unroll
        for (int rr = 0; rr < 4; ++rr)
          qs[(rowb + 4 * g + rr) * HH + nf * 16 + r] = f2bf(acc[mf][i][rr] * QSCALE);
      } else if (m == 1) {
#pragma unroll
        for (int rr = 0; rr < 4; ++rr)
          ks_[(rowb + 4 * g + rr) * HH + nf * 16 + r] = f2bf(acc[mf][i][rr]);
      } else {
#pragma unroll
        for (int rr = 0; rr < 4; ++rr)
          vt[(nf * 16 + r) * 72 + ms * 32 + mf * 16 + 4 * g + rr] = f2bf(acc[mf][i][rr]);
      }
    }
  }
  __syncthreads();
  if (tid < 256) {
    const int h = tid >> 2;
    const int seg = (tid & 3) * 16;
    const u16* s = &vt[h * 72 + seg];
    u16* d = &vsT[(b * HH + h) * LL + kvloc + seg];
    *(short8*)d = *(short8*)s;
    *(short8*)(d + 8) = *(short8*)(s + 8);
  }
}

// ---------------------------------------------------------------------------
// Kernel 2: causal flash attention, 32x32 swapped MFMA, all-in-register
// softmax. Per wave: 32 q-rows x 32 kv per step; S^T = mfma(K, Q) so lane
// owns q-row (lane&31): row reduce = 15 in-lane + 1 shfl_xor(32). O computed
// transposed (O^T = V^T P^T): rescale in-lane; P -> PV B-frag via cvt_pk +
// shfl_xor(32), ZERO LDS / barriers in the loop. kv-split: qt32>=16 even
// 2-way; block order longest-first; batch -> XCD.
// ---------------------------------------------------------------------------
__global__ __launch_bounds__(256, 4) void attn(const u16* __restrict__ qs,
                                               const u16* __restrict__ ks,
                                               const u16* __restrict__ vsT,
                                               float* __restrict__ out,
                                               float* __restrict__ part) {
  __shared__ float oM[4][32 * 65];
  __shared__ float ml[4][2][32];

  const int bi = blockIdx.x;
  const int cid = bi >> 3;
  const int b = bi & 7;                // batch -> XCD pinning
  int qt, t0, t1, chunk;
  if (cid < 96) {                      // qt32 16..63, 2 chunks each
    qt = 63 - (cid >> 1);
    chunk = cid & 1;
    const int tmid = (qt + 1) >> 1;
    t0 = chunk ? tmid : 0;
    t1 = chunk ? (qt + 1) : tmid;
  } else {                             // qt32 0..15, single
    qt = 111 - cid; chunk = -1; t0 = 0; t1 = qt + 1;
  }
  const int q0 = qt * 32;

  const int tid = threadIdx.x;
  const int lane = tid & 63;
  const int wv = tid >> 6;
  const int l31 = lane & 31;
  const int hi = lane >> 5;

  // Q B-frags (persistent): col=q0+l31, k(dim)=16i+8hi+j
  const u16* qp = &qs[(b * LL + q0 + l31) * HH + 8 * hi];
  const short8 qf0 = *(const short8*)(qp);
  const short8 qf1 = *(const short8*)(qp + 16);
  const short8 qf2 = *(const short8*)(qp + 32);
  const short8 qf3 = *(const short8*)(qp + 48);

  float mrun = -1e30f, lrun = 0.0f;    // state for q-row q0+l31 (dup per hi)
  f32x16 ot0 = {}, ot1 = {};           // O^T: col=q=l31, rows h

  const u16* kbase = &ks[(size_t)(b * LL) * HH + 8 * hi];
  const u16* vb0 = &vsT[(size_t)(b * HH + l31) * LL + 8 * hi];
  const u16* vb1 = &vsT[(size_t)(b * HH + 32 + l31) * LL + 8 * hi];

  for (int t = t0 + wv; t < t1; t += 4) {
    const int kv0 = t << 5;
    // ---- A-frags = K rows (kv0+l31), 4 k-chunks of head dim
    const u16* kp = kbase + (kv0 + l31) * HH;
    short8 ka0 = *(const short8*)(kp);
    short8 ka1 = *(const short8*)(kp + 16);
    short8 ka2 = *(const short8*)(kp + 32);
    short8 ka3 = *(const short8*)(kp + 48);
    f32x16 s = {};
    __builtin_amdgcn_s_setprio(1);
    s = mfma32(ka0, qf0, s);
    s = mfma32(ka1, qf1, s);
    s = mfma32(ka2, qf2, s);
    s = mfma32(ka3, qf3, s);
    __builtin_amdgcn_s_setprio(0);
    // ---- V^T A-frags (issue early; consumed after softmax)
    short8 va00 = *(const short8*)(vb0 + kv0);        // hb=0, kv c=0
    short8 va01 = *(const short8*)(vb0 + kv0 + 16);   // hb=0, c=1
    short8 va10 = *(const short8*)(vb1 + kv0);        // hb=1, c=0
    short8 va11 = *(const short8*)(vb1 + kv0 + 16);   // hb=1, c=1
    // ---- causal mask (only the diagonal tile t == qt)
    if (t == qt) {
      const int thr = l31 - 4 * hi;    // kv0 == q0 here
#pragma unroll
      for (int e = 0; e < 16; ++e)
        if (((e & 3) + 8 * (e >> 2)) > thr) s[e] = -1e30f;
    }
    // ---- row max (q-row = l31): in-lane 16 + cross-half
    float pm = s[0];
#pragma unroll
    for (int e = 1; e < 16; ++e) pm = fmaxf(pm, s[e]);
    pm = fmaxf(pm, __shfl_xor(pm, 32));
    const float nm = fmaxf(mrun, pm);
    const float al = exp2x(mrun - nm);
    // ---- p = exp2(s - nm), row sum
    float rs = 0.0f;
#pragma unroll
    for (int e = 0; e < 16; ++e) {
      float p = exp2x(s[e] - nm);
      s[e] = p;
      rs += p;
    }
    rs += __shfl_xor(rs, 32);
    lrun = lrun * al + rs;
    mrun = nm;
    // ---- pack P to bf16 dwords; lane holds kv = 8t+4hi+{0..3} per pair t
    u32 p0x = cvtpk(s[0], s[1]),   p0y = cvtpk(s[2], s[3]);    // dw 2hi,  +1
    u32 p1x = cvtpk(s[4], s[5]),   p1y = cvtpk(s[6], s[7]);    // dw 4+2hi,+1
    u32 p2x = cvtpk(s[8], s[9]),   p2y = cvtpk(s[10], s[11]);  // dw 8+2hi,+1
    u32 p3x = cvtpk(s[12], s[13]), p3y = cvtpk(s[14], s[15]);  // dw 12+2hi
    // ---- cross-half exchange -> B-frag (col=q=l31, k=kv)
    u32 x0x = __shfl_xor(p0x, 32), x0y = __shfl_xor(p0y, 32);
    u32 x1x = __shfl_xor(p1x, 32), x1y = __shfl_xor(p1y, 32);
    u32 x2x = __shfl_xor(p2x, 32), x2y = __shfl_xor(p2y, 32);
    u32 x3x = __shfl_xor(p3x, 32), x3y = __shfl_xor(p3y, 32);
    // frag c0: k = kv0 + 8hi + j  -> dwords [4hi .. 4hi+3]
    u32x4 w0 = { hi ? x1x : p0x, hi ? x1y : p0y,
                 hi ? p1x : x0x, hi ? p1y : x0y };
    // frag c1: k = kv0 + 16 + 8hi + j -> dwords [8+4hi .. +3]
    u32x4 w1 = { hi ? x3x : p2x, hi ? x3y : p2y,
                 hi ? p3x : x2x, hi ? p3y : x2y };
    short8 pb0 = __builtin_bit_cast(short8, w0);
    short8 pb1 = __builtin_bit_cast(short8, w1);
    // ---- rescale O^T (all values belong to q-row l31) and accumulate PV
#pragma unroll
    for (int e = 0; e < 16; ++e) { ot0[e] *= al; ot1[e] *= al; }
    __builtin_amdgcn_s_setprio(1);
    ot0 = mfma32(va00, pb0, ot0);
    ot0 = mfma32(va01, pb1, ot0);
    ot1 = mfma32(va10, pb0, ot1);
    ot1 = mfma32(va11, pb1, ot1);
    __builtin_amdgcn_s_setprio(0);
  }

  // ---- per-wave partials to LDS (stride 65: conflict-free)
#pragma unroll
  for (int e = 0; e < 16; ++e) {
    const int hrow = (e & 3) + 8 * (e >> 2) + 4 * hi;
    oM[wv][l31 * 65 + hrow] = ot0[e];
    oM[wv][l31 * 65 + 32 + hrow] = ot1[e];
  }
  if (hi == 0) {
    ml[wv][0][l31] = mrun;
    ml[wv][1][l31] = lrun;
  }
  __syncthreads();

  // ---- merge 4 waves: thread = (row, 8 h-cols)
  {
    const int row = tid >> 3;          // 0..31
    const int h8 = (tid & 7) * 8;      // 0..56
    float M = ml[0][0][row];
#pragma unroll
    for (int w = 1; w < 4; ++w) M = fmaxf(M, ml[w][0][row]);
    float L = 0.0f;
    float O[8] = {};
#pragma unroll
    for (int w = 0; w < 4; ++w) {
      const float aw = exp2x(ml[w][0][row] - M);
      L += ml[w][1][row] * aw;
#pragma unroll
      for (int j = 0; j < 8; ++j)
        O[j] += oM[w][row * 65 + h8 + j] * aw;
    }
    if (chunk < 0) {
      const float inv = 1.0f / L;
      float4 r0 = { O[0] * inv, O[1] * inv, O[2] * inv, O[3] * inv };
      float4 r1 = { O[4] * inv, O[5] * inv, O[6] * inv, O[7] * inv };
      float* op = &out[(size_t)(b * LL + q0 + row) * HH + h8];
      *(float4*)op = r0;
      *(float4*)(op + 4) = r1;
    } else {
      float* pp = part + (size_t)((b * 48 + (qt - 16)) * 2 + chunk) * PART32;
      if (h8 == 0) { pp[row] = M; pp[32 + row] = L; }
      float* od = &pp[64 + row * 64 + h8];
      float4 r0 = { O[0], O[1], O[2], O[3] };
      float4 r1 = { O[4], O[5], O[6], O[7] };
      *(float4*)od = r0;
      *(float4*)(od + 4) = r1;
    }
  }
}

// ---------------------------------------------------------------------------
// Kernel 3: merge the 2 kv-chunk partials for q-tiles 16..63 (32-row tiles).
// ---------------------------------------------------------------------------
__global__ __launch_bounds__(256) void attn_merge(const float* __restrict__ part,
                                                  float* __restrict__ out) {
  const int bi = blockIdx.x;           // [0, 384) = b*48 + qi
  const int b = bi / 48;
  const int qi = bi % 48;              // qt32 = 16 + qi
  const float* p0 = part + (size_t)((b * 48 + qi) * 2 + 0) * PART32;
  const float* p1 = part + (size_t)((b * 48 + qi) * 2 + 1) * PART32;
  const int row = threadIdx.x >> 3;
  const int h8 = (threadIdx.x & 7) * 8;
  const float m0 = p0[row], l0 = p0[32 + row];
  const float m1 = p1[row], l1 = p1[32 + row];
  const float M = fmaxf(m0, m1);
  const float a0 = exp2x(m0 - M), a1 = exp2x(m1 - M);
  const float inv = 1.0f / (l0 * a0 + l1 * a1);
  const float* o0 = &p0[64 + row * 64 + h8];
  const float* o1 = &p1[64 + row * 64 + h8];
  float4 A0 = *(const float4*)o0, B0 = *(const float4*)o1;
  float4 A1 = *(const float4*)(o0 + 4), B1 = *(const float4*)(o1 + 4);
  float4 r0 = { (A0.x * a0 + B0.x * a1) * inv, (A0.y * a0 + B0.y * a1) * inv,
                (A0.z * a0 + B0.z * a1) * inv, (A0.w * a0 + B0.w * a1) * inv };
  float4 r1 = { (A1.x * a0 + B1.x * a1) * inv, (A1.y * a0 + B1.y * a1) * inv,
                (A1.z * a0 + B1.z * a1) * inv, (A1.w * a0 + B1.w * a1) * inv };
  float* op = &out[(size_t)(b * LL + (16 + qi) * 32 + row) * HH + h8];
  *(float4*)op = r0;
  *(float4*)(op + 4) = r1;
}

extern "C" void kernel_launch(void* const* d_in, const int* in_sizes, int n_in,
                              void* d_out, int out_size, void* d_ws, size_t ws_size,
                              hipStream_t stream) {
  const float* x  = (const float*)d_in[0];
  const float* Wk = (const float*)d_in[1];
  const float* Wq = (const float*)d_in[2];
  const float* Wv = (const float*)d_in[3];

  u16* qs  = (u16*)d_ws;             // [16384][64] bf16
  u16* ks  = qs + BL * HH;           // [16384][64] bf16
  u16* vsT = ks + BL * HH;           // [8][64][2048] bf16 (V transposed)
  u16* wtp = vsT + BL * HH;          // [384][512] bf16 (W in frag order)
  float* part = (float*)(wtp + 384 * 512);  // [8*48][2][PART32] f32

  wtp_pack<<<96, 256, 0, stream>>>(Wq, Wk, Wv, wtp);
  qkv_proj<<<BL / 64, 512, 0, stream>>>(x, wtp, qs, ks, vsT);
  attn<<<112 * BQ, 256, 0, stream>>>(qs, ks, vsT, (float*)d_out, part);
  attn_merge<<<384, 256, 0, stream>>>(part, (float*)d_out);
}

// Round 11
// 55.304 us; speedup vs baseline: 1.5166x; 1.0503x over previous
//
#include <hip/hip_runtime.h>
#include <hip/hip_bf16.h>

typedef __attribute__((ext_vector_type(8))) short short8;
typedef __attribute__((ext_vector_type(8))) float f32x8;
typedef __attribute__((ext_vector_type(4))) float f32x4;
typedef __attribute__((ext_vector_type(16))) float f32x16;
typedef __attribute__((ext_vector_type(4))) unsigned int u32x4;
typedef unsigned short u16;
typedef unsigned int u32;

#define BQ 8
#define LL 2048
#define NN 1024
#define HH 64
#define BL (BQ * LL) /* 16384 */
#define PART32 2112   /* floats per attn partial: 32 m + 32 l + 32x64 O */
#define QSCALE 0.0450842213f  /* (1/32) * log2(e): exp2-domain softmax */

static __device__ __forceinline__ u16 f2bf(float f) {
  union { float f; unsigned int u; } cv;
  cv.f = f;
  unsigned int u = cv.u;
  unsigned int rounded = u + 0x7FFFu + ((u >> 16) & 1u);  // RNE
  return (u16)(rounded >> 16);
}

static __device__ __forceinline__ float exp2x(float x) {
  return __builtin_amdgcn_exp2f(x);
}

// pack two f32 -> one dword of 2 bf16 (lo = first arg)
static __device__ __forceinline__ u32 cvtpk(float lo, float hi) {
  u32 d;
  asm("v_cvt_pk_bf16_f32 %0, %1, %2" : "=v"(d) : "v"(lo), "v"(hi));
  return d;
}

// pack 8 f32 -> 8 bf16 by truncation (1 v_perm per 2 elements)
static __device__ __forceinline__ short8 pack_bf16(f32x8 v) {
  short8 o;
  u32* op = (u32*)&o;
#pragma unroll
  for (int w = 0; w < 4; ++w) {
    op[w] = __builtin_amdgcn_perm(__float_as_uint(v[2 * w + 1]),
                                  __float_as_uint(v[2 * w]), 0x07060302u);
  }
  return o;
}

// async global -> LDS, 16B per lane; lds dest must be wave-uniform base
static __device__ __forceinline__ void gload_lds16(const u16* g, u16* l) {
  __builtin_amdgcn_global_load_lds(
      (const __attribute__((address_space(1))) unsigned int*)g,
      (__attribute__((address_space(3))) unsigned int*)l, 16, 0, 0);
}

static __device__ __forceinline__ f32x16 mfma32(short8 a, short8 b, f32x16 c) {
  return __builtin_amdgcn_mfma_f32_32x32x16_bf16(a, b, c, 0, 0, 0);
}

// ---------------------------------------------------------------------------
// Kernel 0: pack W into MFMA B-fragment order (unchanged).
// ---------------------------------------------------------------------------
__global__ __launch_bounds__(256) void wtp_pack(const float* __restrict__ Wq,
                                                const float* __restrict__ Wk,
                                                const float* __restrict__ Wv,
                                                u16* __restrict__ wtp) {
  int gid = blockIdx.x * 256 + threadIdx.x;   // [0, 384*64)
  int f = gid >> 6;
  int l = gid & 63;
  int m = f >> 7;
  int rem = f & 127;
  int nf = rem >> 5;
  int ks = rem & 31;
  int r = l & 15;
  int g = l >> 4;
  const float* src = (m == 0) ? Wq : (m == 1) ? Wk : Wv;
  short8 o;
#pragma unroll
  for (int j = 0; j < 8; ++j)
    o[j] = (short)f2bf(src[(ks * 32 + 8 * g + j) * HH + nf * 16 + r]);
  *(short8*)&wtp[f * 512 + l * 8] = o;
}

// ---------------------------------------------------------------------------
// Kernel 1: qkv projection, LDS-staged GEMM, 2-deep x register prefetch
// (HBM ~600-900cyc covered by two chunks of compute instead of one).
// ---------------------------------------------------------------------------
__global__ __launch_bounds__(512, 4) void qkv_proj(const float* __restrict__ x,
                                                   const u16* __restrict__ wtp,
                                                   u16* __restrict__ qs,
                                                   u16* __restrict__ ks_,
                                                   u16* __restrict__ vsT) {
  __shared__ u16 xs[2][64 * 72];     // x tile, row stride 72
  __shared__ u16 ws[2][24 * 512];    // W frags: c = F*2 + ks, frag-linear

  const int row0 = blockIdx.x * 64;
  const int tid = threadIdx.x;
  const int wv = tid >> 6;
  const int lane = tid & 63;
  const int r = lane & 15;
  const int g = lane >> 4;
  const int ms = wv >> 2;            // 32-row half
  const int fq = wv & 3;             // 3-F quarter

  const int srow = tid >> 3;         // 0..63
  const int scol = (tid & 7) * 8;    // 0..56
  const float* xsrc = x + (row0 + srow) * NN + scol;

  f32x4 acc[2][3] = {};

  // ---- prologue: chunk 0 to LDS; chunk 1 into regs
  f32x8 xra;
  {
    f32x8 xv = *(const f32x8*)xsrc;
    *(short8*)&xs[0][srow * 72 + scol] = pack_bf16(xv);
#pragma unroll
    for (int j = 0; j < 3; ++j) {
      int c = wv * 3 + j;
      int F = c >> 1, ks = c & 1;
      int gf = F * 32 + ks;
      gload_lds16(wtp + gf * 512 + lane * 8, &ws[0][c * 512]);
    }
    xra = *(const f32x8*)(xsrc + 64);
  }
  __syncthreads();

  int cur = 0;
  for (int kc = 0; kc < 16; ++kc) {
    f32x8 xrb;
    if (kc < 14) xrb = *(const f32x8*)(xsrc + (kc + 2) * 64);
    if (kc < 15) {
#pragma unroll
      for (int j = 0; j < 3; ++j) {
        int c = wv * 3 + j;
        int F = c >> 1, ks = c & 1;
        int gf = F * 32 + (kc + 1) * 2 + ks;
        gload_lds16(wtp + gf * 512 + lane * 8, &ws[cur ^ 1][c * 512]);
      }
    }
#pragma unroll
    for (int ks = 0; ks < 2; ++ks) {
      short8 a[2];
#pragma unroll
      for (int mf = 0; mf < 2; ++mf)
        a[mf] = *(const short8*)&xs[cur][(ms * 32 + mf * 16 + r) * 72 + ks * 32 + 8 * g];
#pragma unroll
      for (int i = 0; i < 3; ++i) {
        int c = (fq * 3 + i) * 2 + ks;
        short8 bfr = *(const short8*)&ws[cur][c * 512 + lane * 8];
#pragma unroll
        for (int mf = 0; mf < 2; ++mf)
          acc[mf][i] = __builtin_amdgcn_mfma_f32_16x16x32_bf16(a[mf], bfr, acc[mf][i], 0, 0, 0);
      }
    }
    if (kc < 15) {
      *(short8*)&xs[cur ^ 1][srow * 72 + scol] = pack_bf16(xra);
      xra = xrb;
    }
    __syncthreads();
    cur ^= 1;
  }

  const int b = row0 >> 11;
  const int kvloc = row0 & (LL - 1);
  u16* vt = xs[0];
#pragma unroll
  for (int mf = 0; mf < 2; ++mf) {
#pragma unroll
    for (int i = 0; i < 3; ++i) {
      const int F = fq * 3 + i, m = F >> 2, nf = F & 3;
      const int rowb = row0 + ms * 32 + mf * 16;
      if (m == 0) {
#pragma unroll
        for (int rr = 0; rr < 4; ++rr)
          qs[(rowb + 4 * g + rr) * HH + nf * 16 + r] = f2bf(acc[mf][i][rr] * QSCALE);
      } else if (m == 1) {
#pragma unroll
        for (int rr = 0; rr < 4; ++rr)
          ks_[(rowb + 4 * g + rr) * HH + nf * 16 + r] = f2bf(acc[mf][i][rr]);
      } else {
#pragma unroll
        for (int rr = 0; rr < 4; ++rr)
          vt[(nf * 16 + r) * 72 + ms * 32 + mf * 16 + 4 * g + rr] = f2bf(acc[mf][i][rr]);
      }
    }
  }
  __syncthreads();
  if (tid < 256) {
    const int h = tid >> 2;
    const int seg = (tid & 3) * 16;
    const u16* s = &vt[h * 72 + seg];
    u16* d = &vsT[(b * HH + h) * LL + kvloc + seg];
    *(short8*)d = *(short8*)s;
    *(short8*)(d + 8) = *(short8*)(s + 8);
  }
}

// ---------------------------------------------------------------------------
// Kernel 2: causal flash attention, 32x32 swapped MFMA, in-register softmax.
// launch_bounds (256,3): 170-VGPR cap -> no scratch spill (the r10 risk).
// V^T loads staggered JIT (two pairs) to cut peak register pressure.
// ---------------------------------------------------------------------------
__global__ __launch_bounds__(256, 3) void attn(const u16* __restrict__ qs,
                                               const u16* __restrict__ ks,
                                               const u16* __restrict__ vsT,
                                               float* __restrict__ out,
                                               float* __restrict__ part) {
  __shared__ float oM[4][32 * 65];
  __shared__ float ml[4][2][32];

  const int bi = blockIdx.x;
  const int cid = bi >> 3;
  const int b = bi & 7;                // batch -> XCD pinning
  int qt, t0, t1, chunk;
  if (cid < 96) {                      // qt32 16..63, 2 chunks each
    qt = 63 - (cid >> 1);
    chunk = cid & 1;
    const int tmid = (qt + 1) >> 1;
    t0 = chunk ? tmid : 0;
    t1 = chunk ? (qt + 1) : tmid;
  } else {                             // qt32 0..15, single
    qt = 111 - cid; chunk = -1; t0 = 0; t1 = qt + 1;
  }
  const int q0 = qt * 32;

  const int tid = threadIdx.x;
  const int lane = tid & 63;
  const int wv = tid >> 6;
  const int l31 = lane & 31;
  const int hi = lane >> 5;

  // Q B-frags (persistent): col=q0+l31, k(dim)=16i+8hi+j
  const u16* qp = &qs[(b * LL + q0 + l31) * HH + 8 * hi];
  const short8 qf0 = *(const short8*)(qp);
  const short8 qf1 = *(const short8*)(qp + 16);
  const short8 qf2 = *(const short8*)(qp + 32);
  const short8 qf3 = *(const short8*)(qp + 48);

  float mrun = -1e30f, lrun = 0.0f;    // state for q-row q0+l31 (dup per hi)
  f32x16 ot0 = {}, ot1 = {};           // O^T: col=q=l31, rows h

  const u16* kbase = &ks[(size_t)(b * LL) * HH + 8 * hi];
  const u16* vb0 = &vsT[(size_t)(b * HH + l31) * LL + 8 * hi];
  const u16* vb1 = &vsT[(size_t)(b * HH + 32 + l31) * LL + 8 * hi];

  for (int t = t0 + wv; t < t1; t += 4) {
    const int kv0 = t << 5;
    // ---- A-frags = K rows (kv0+l31), 4 k-chunks of head dim
    const u16* kp = kbase + (kv0 + l31) * HH;
    short8 ka0 = *(const short8*)(kp);
    short8 ka1 = *(const short8*)(kp + 16);
    short8 ka2 = *(const short8*)(kp + 32);
    short8 ka3 = *(const short8*)(kp + 48);
    f32x16 s = {};
    __builtin_amdgcn_s_setprio(1);
    s = mfma32(ka0, qf0, s);
    s = mfma32(ka1, qf1, s);
    s = mfma32(ka2, qf2, s);
    s = mfma32(ka3, qf3, s);
    __builtin_amdgcn_s_setprio(0);
    // ---- V^T pair 0 (hb=0): issue under softmax
    short8 va00 = *(const short8*)(vb0 + kv0);        // hb=0, kv c=0
    short8 va01 = *(const short8*)(vb0 + kv0 + 16);   // hb=0, c=1
    // ---- causal mask (only the diagonal tile t == qt)
    if (t == qt) {
      const int thr = l31 - 4 * hi;    // kv0 == q0 here
#pragma unroll
      for (int e = 0; e < 16; ++e)
        if (((e & 3) + 8 * (e >> 2)) > thr) s[e] = -1e30f;
    }
    // ---- row max (q-row = l31): in-lane 16 + cross-half
    float pm = s[0];
#pragma unroll
    for (int e = 1; e < 16; ++e) pm = fmaxf(pm, s[e]);
    pm = fmaxf(pm, __shfl_xor(pm, 32));
    const float nm = fmaxf(mrun, pm);
    const float al = exp2x(mrun - nm);
    // ---- p = exp2(s - nm), row sum
    float rs = 0.0f;
#pragma unroll
    for (int e = 0; e < 16; ++e) {
      float p = exp2x(s[e] - nm);
      s[e] = p;
      rs += p;
    }
    rs += __shfl_xor(rs, 32);
    lrun = lrun * al + rs;
    mrun = nm;
    // ---- pack P to bf16 dwords; lane holds kv = 8t+4hi+{0..3} per pair t
    u32 p0x = cvtpk(s[0], s[1]),   p0y = cvtpk(s[2], s[3]);
    u32 p1x = cvtpk(s[4], s[5]),   p1y = cvtpk(s[6], s[7]);
    u32 p2x = cvtpk(s[8], s[9]),   p2y = cvtpk(s[10], s[11]);
    u32 p3x = cvtpk(s[12], s[13]), p3y = cvtpk(s[14], s[15]);
    // ---- V^T pair 1 (hb=1): issue under the cross-half exchange
    short8 va10 = *(const short8*)(vb1 + kv0);        // hb=1, c=0
    short8 va11 = *(const short8*)(vb1 + kv0 + 16);   // hb=1, c=1
    // ---- cross-half exchange -> B-frag (col=q=l31, k=kv)
    u32 x0x = __shfl_xor(p0x, 32), x0y = __shfl_xor(p0y, 32);
    u32 x1x = __shfl_xor(p1x, 32), x1y = __shfl_xor(p1y, 32);
    u32 x2x = __shfl_xor(p2x, 32), x2y = __shfl_xor(p2y, 32);
    u32 x3x = __shfl_xor(p3x, 32), x3y = __shfl_xor(p3y, 32);
    u32x4 w0 = { hi ? x1x : p0x, hi ? x1y : p0y,
                 hi ? p1x : x0x, hi ? p1y : x0y };
    u32x4 w1 = { hi ? x3x : p2x, hi ? x3y : p2y,
                 hi ? p3x : x2x, hi ? p3y : x2y };
    short8 pb0 = __builtin_bit_cast(short8, w0);
    short8 pb1 = __builtin_bit_cast(short8, w1);
    // ---- rescale O^T (all values belong to q-row l31) and accumulate PV
#pragma unroll
    for (int e = 0; e < 16; ++e) { ot0[e] *= al; ot1[e] *= al; }
    __builtin_amdgcn_s_setprio(1);
    ot0 = mfma32(va00, pb0, ot0);
    ot0 = mfma32(va01, pb1, ot0);
    ot1 = mfma32(va10, pb0, ot1);
    ot1 = mfma32(va11, pb1, ot1);
    __builtin_amdgcn_s_setprio(0);
  }

  // ---- per-wave partials to LDS (stride 65: conflict-free)
#pragma unroll
  for (int e = 0; e < 16; ++e) {
    const int hrow = (e & 3) + 8 * (e >> 2) + 4 * hi;
    oM[wv][l31 * 65 + hrow] = ot0[e];
    oM[wv][l31 * 65 + 32 + hrow] = ot1[e];
  }
  if (hi == 0) {
    ml[wv][0][l31] = mrun;
    ml[wv][1][l31] = lrun;
  }
  __syncthreads();

  // ---- merge 4 waves: thread = (row, 8 h-cols)
  {
    const int row = tid >> 3;          // 0..31
    const int h8 = (tid & 7) * 8;      // 0..56
    float M = ml[0][0][row];
#pragma unroll
    for (int w = 1; w < 4; ++w) M = fmaxf(M, ml[w][0][row]);
    float L = 0.0f;
    float O[8] = {};
#pragma unroll
    for (int w = 0; w < 4; ++w) {
      const float aw = exp2x(ml[w][0][row] - M);
      L += ml[w][1][row] * aw;
#pragma unroll
      for (int j = 0; j < 8; ++j)
        O[j] += oM[w][row * 65 + h8 + j] * aw;
    }
    if (chunk < 0) {
      const float inv = 1.0f / L;
      float4 r0 = { O[0] * inv, O[1] * inv, O[2] * inv, O[3] * inv };
      float4 r1 = { O[4] * inv, O[5] * inv, O[6] * inv, O[7] * inv };
      float* op = &out[(size_t)(b * LL + q0 + row) * HH + h8];
      *(float4*)op = r0;
      *(float4*)(op + 4) = r1;
    } else {
      float* pp = part + (size_t)((b * 48 + (qt - 16)) * 2 + chunk) * PART32;
      if (h8 == 0) { pp[row] = M; pp[32 + row] = L; }
      float* od = &pp[64 + row * 64 + h8];
      float4 r0 = { O[0], O[1], O[2], O[3] };
      float4 r1 = { O[4], O[5], O[6], O[7] };
      *(float4*)od = r0;
      *(float4*)(od + 4) = r1;
    }
  }
}

// ---------------------------------------------------------------------------
// Kernel 3: merge the 2 kv-chunk partials for q-tiles 16..63 (32-row tiles).
// ---------------------------------------------------------------------------
__global__ __launch_bounds__(256) void attn_merge(const float* __restrict__ part,
                                                  float* __restrict__ out) {
  const int bi = blockIdx.x;           // [0, 384) = b*48 + qi
  const int b = bi / 48;
  const int qi = bi % 48;              // qt32 = 16 + qi
  const float* p0 = part + (size_t)((b * 48 + qi) * 2 + 0) * PART32;
  const float* p1 = part + (size_t)((b * 48 + qi) * 2 + 1) * PART32;
  const int row = threadIdx.x >> 3;
  const int h8 = (threadIdx.x & 7) * 8;
  const float m0 = p0[row], l0 = p0[32 + row];
  const float m1 = p1[row], l1 = p1[32 + row];
  const float M = fmaxf(m0, m1);
  const float a0 = exp2x(m0 - M), a1 = exp2x(m1 - M);
  const float inv = 1.0f / (l0 * a0 + l1 * a1);
  const float* o0 = &p0[64 + row * 64 + h8];
  const float* o1 = &p1[64 + row * 64 + h8];
  float4 A0 = *(const float4*)o0, B0 = *(const float4*)o1;
  float4 A1 = *(const float4*)(o0 + 4), B1 = *(const float4*)(o1 + 4);
  float4 r0 = { (A0.x * a0 + B0.x * a1) * inv, (A0.y * a0 + B0.y * a1) * inv,
                (A0.z * a0 + B0.z * a1) * inv, (A0.w * a0 + B0.w * a1) * inv };
  float4 r1 = { (A1.x * a0 + B1.x * a1) * inv, (A1.y * a0 + B1.y * a1) * inv,
                (A1.z * a0 + B1.z * a1) * inv, (A1.w * a0 + B1.w * a1) * inv };
  float* op = &out[(size_t)(b * LL + (16 + qi) * 32 + row) * HH + h8];
  *(float4*)op = r0;
  *(float4*)(op + 4) = r1;
}

extern "C" void kernel_launch(void* const* d_in, const int* in_sizes, int n_in,
                              void* d_out, int out_size, void* d_ws, size_t ws_size,
                              hipStream_t stream) {
  const float* x  = (const float*)d_in[0];
  const float* Wk = (const float*)d_in[1];
  const float* Wq = (const float*)d_in[2];
  const float* Wv = (const float*)d_in[3];

  u16* qs  = (u16*)d_ws;             // [16384][64] bf16
  u16* ks  = qs + BL * HH;           // [16384][64] bf16
  u16* vsT = ks + BL * HH;           // [8][64][2048] bf16 (V transposed)
  u16* wtp = vsT + BL * HH;          // [384][512] bf16 (W in frag order)
  float* part = (float*)(wtp + 384 * 512);  // [8*48][2][PART32] f32

  wtp_pack<<<96, 256, 0, stream>>>(Wq, Wk, Wv, wtp);
  qkv_proj<<<BL / 64, 512, 0, stream>>>(x, wtp, qs, ks, vsT);
  attn<<<112 * BQ, 256, 0, stream>>>(qs, ks, vsT, (float*)d_out, part);
  attn_merge<<<384, 256, 0, stream>>>(part, (float*)d_out);
}

// Round 12
// 48.907 us; speedup vs baseline: 1.7149x; 1.1308x over previous
//
#include <hip/hip_runtime.h>
#include <hip/hip_bf16.h>

typedef __attribute__((ext_vector_type(8))) short short8;
typedef __attribute__((ext_vector_type(8))) float f32x8;
typedef __attribute__((ext_vector_type(4))) float f32x4;
typedef __attribute__((ext_vector_type(16))) float f32x16;
typedef __attribute__((ext_vector_type(4))) unsigned int u32x4;
typedef unsigned short u16;
typedef unsigned int u32;

#define BQ 8
#define LL 2048
#define NN 1024
#define HH 64
#define BL (BQ * LL) /* 16384 */
#define PART64 4224   /* floats per attn partial: 64 m + 64 l + 64x64 O */
#define QSCALE 0.0450842213f  /* (1/32) * log2(e): exp2-domain softmax */

static __device__ __forceinline__ u16 f2bf(float f) {
  union { float f; unsigned int u; } cv;
  cv.f = f;
  unsigned int u = cv.u;
  unsigned int rounded = u + 0x7FFFu + ((u >> 16) & 1u);  // RNE
  return (u16)(rounded >> 16);
}

static __device__ __forceinline__ float exp2x(float x) {
  return __builtin_amdgcn_exp2f(x);
}

// pack two f32 -> one dword of 2 bf16 (lo = first arg)
static __device__ __forceinline__ u32 cvtpk(float lo, float hi) {
  u32 d;
  asm("v_cvt_pk_bf16_f32 %0, %1, %2" : "=v"(d) : "v"(lo), "v"(hi));
  return d;
}

// pack 8 f32 -> 8 bf16 by truncation (1 v_perm per 2 elements)
static __device__ __forceinline__ short8 pack_bf16(f32x8 v) {
  short8 o;
  u32* op = (u32*)&o;
#pragma unroll
  for (int w = 0; w < 4; ++w) {
    op[w] = __builtin_amdgcn_perm(__float_as_uint(v[2 * w + 1]),
                                  __float_as_uint(v[2 * w]), 0x07060302u);
  }
  return o;
}

// async global -> LDS, 16B per lane; lds dest must be wave-uniform base
static __device__ __forceinline__ void gload_lds16(const u16* g, u16* l) {
  __builtin_amdgcn_global_load_lds(
      (const __attribute__((address_space(1))) unsigned int*)g,
      (__attribute__((address_space(3))) unsigned int*)l, 16, 0, 0);
}

static __device__ __forceinline__ f32x16 mfma32(short8 a, short8 b, f32x16 c) {
  return __builtin_amdgcn_mfma_f32_32x32x16_bf16(a, b, c, 0, 0, 0);
}

// ---------------------------------------------------------------------------
// Kernel 0: pack W into MFMA B-fragment order (unchanged).
// ---------------------------------------------------------------------------
__global__ __launch_bounds__(256) void wtp_pack(const float* __restrict__ Wq,
                                                const float* __restrict__ Wk,
                                                const float* __restrict__ Wv,
                                                u16* __restrict__ wtp) {
  int gid = blockIdx.x * 256 + threadIdx.x;   // [0, 384*64)
  int f = gid >> 6;
  int l = gid & 63;
  int m = f >> 7;
  int rem = f & 127;
  int nf = rem >> 5;
  int ks = rem & 31;
  int r = l & 15;
  int g = l >> 4;
  const float* src = (m == 0) ? Wq : (m == 1) ? Wk : Wv;
  short8 o;
#pragma unroll
  for (int j = 0; j < 8; ++j)
    o[j] = (short)f2bf(src[(ks * 32 + 8 * g + j) * HH + nf * 16 + r]);
  *(short8*)&wtp[f * 512 + l * 8] = o;
}

// ---------------------------------------------------------------------------
// Kernel 1: qkv projection, LDS-staged GEMM, 2-deep x register prefetch
// (unchanged from r11).
// ---------------------------------------------------------------------------
__global__ __launch_bounds__(512, 4) void qkv_proj(const float* __restrict__ x,
                                                   const u16* __restrict__ wtp,
                                                   u16* __restrict__ qs,
                                                   u16* __restrict__ ks_,
                                                   u16* __restrict__ vsT) {
  __shared__ u16 xs[2][64 * 72];     // x tile, row stride 72
  __shared__ u16 ws[2][24 * 512];    // W frags: c = F*2 + ks, frag-linear

  const int row0 = blockIdx.x * 64;
  const int tid = threadIdx.x;
  const int wv = tid >> 6;
  const int lane = tid & 63;
  const int r = lane & 15;
  const int g = lane >> 4;
  const int ms = wv >> 2;            // 32-row half
  const int fq = wv & 3;             // 3-F quarter

  const int srow = tid >> 3;         // 0..63
  const int scol = (tid & 7) * 8;    // 0..56
  const float* xsrc = x + (row0 + srow) * NN + scol;

  f32x4 acc[2][3] = {};

  // ---- prologue: chunk 0 to LDS; chunk 1 into regs
  f32x8 xra;
  {
    f32x8 xv = *(const f32x8*)xsrc;
    *(short8*)&xs[0][srow * 72 + scol] = pack_bf16(xv);
#pragma unroll
    for (int j = 0; j < 3; ++j) {
      int c = wv * 3 + j;
      int F = c >> 1, ks = c & 1;
      int gf = F * 32 + ks;
      gload_lds16(wtp + gf * 512 + lane * 8, &ws[0][c * 512]);
    }
    xra = *(const f32x8*)(xsrc + 64);
  }
  __syncthreads();

  int cur = 0;
  for (int kc = 0; kc < 16; ++kc) {
    f32x8 xrb;
    if (kc < 14) xrb = *(const f32x8*)(xsrc + (kc + 2) * 64);
    if (kc < 15) {
#pragma unroll
      for (int j = 0; j < 3; ++j) {
        int c = wv * 3 + j;
        int F = c >> 1, ks = c & 1;
        int gf = F * 32 + (kc + 1) * 2 + ks;
        gload_lds16(wtp + gf * 512 + lane * 8, &ws[cur ^ 1][c * 512]);
      }
    }
#pragma unroll
    for (int ks = 0; ks < 2; ++ks) {
      short8 a[2];
#pragma unroll
      for (int mf = 0; mf < 2; ++mf)
        a[mf] = *(const short8*)&xs[cur][(ms * 32 + mf * 16 + r) * 72 + ks * 32 + 8 * g];
#pragma unroll
      for (int i = 0; i < 3; ++i) {
        int c = (fq * 3 + i) * 2 + ks;
        short8 bfr = *(const short8*)&ws[cur][c * 512 + lane * 8];
#pragma unroll
        for (int mf = 0; mf < 2; ++mf)
          acc[mf][i] = __builtin_amdgcn_mfma_f32_16x16x32_bf16(a[mf], bfr, acc[mf][i], 0, 0, 0);
      }
    }
    if (kc < 15) {
      *(short8*)&xs[cur ^ 1][srow * 72 + scol] = pack_bf16(xra);
      xra = xrb;
    }
    __syncthreads();
    cur ^= 1;
  }

  const int b = row0 >> 11;
  const int kvloc = row0 & (LL - 1);
  u16* vt = xs[0];
#pragma unroll
  for (int mf = 0; mf < 2; ++mf) {
#pragma unroll
    for (int i = 0; i < 3; ++i) {
      const int F = fq * 3 + i, m = F >> 2, nf = F & 3;
      const int rowb = row0 + ms * 32 + mf * 16;
      if (m == 0) {
#pragma unroll
        for (int rr = 0; rr < 4; ++rr)
          qs[(rowb + 4 * g + rr) * HH + nf * 16 + r] = f2bf(acc[mf][i][rr] * QSCALE);
      } else if (m == 1) {
#pragma unroll
        for (int rr = 0; rr < 4; ++rr)
          ks_[(rowb + 4 * g + rr) * HH + nf * 16 + r] = f2bf(acc[mf][i][rr]);
      } else {
#pragma unroll
        for (int rr = 0; rr < 4; ++rr)
          vt[(nf * 16 + r) * 72 + ms * 32 + mf * 16 + 4 * g + rr] = f2bf(acc[mf][i][rr]);
      }
    }
  }
  __syncthreads();
  if (tid < 256) {
    const int h = tid >> 2;
    const int seg = (tid & 3) * 16;
    const u16* s = &vt[h * 72 + seg];
    u16* d = &vsT[(b * HH + h) * LL + kvloc + seg];
    *(short8*)d = *(short8*)s;
    *(short8*)(d + 8) = *(short8*)(s + 8);
  }
}

// ---------------------------------------------------------------------------
// Kernel 2: causal flash attention. Per wave: 64 q-rows (2 sub-tiles sharing
// K loads) x 32 kv per step, 32x32 swapped MFMA, in-register softmax.
// launch_bounds (256,2): 256-VGPR cap, definitively spill-free (~200 live).
// Grid 448 = single scheduling generation at 2 blocks/CU.
// nm clamped to -1e20 so a fully-masked first tile yields P=0 (t=2qt+1 sub0).
// ---------------------------------------------------------------------------
__global__ __launch_bounds__(256, 2) void attn(const u16* __restrict__ qs,
                                               const u16* __restrict__ ks,
                                               const u16* __restrict__ vsT,
                                               float* __restrict__ out,
                                               float* __restrict__ part) {
  __shared__ float oM[4][64 * 65];
  __shared__ float ml[4][2][64];

  const int bi = blockIdx.x;
  const int cid = bi >> 3;
  const int b = bi & 7;                // batch -> XCD pinning
  int qt, t0, t1, chunk;
  if (cid < 48) {                      // qt64 8..31: 2 chunks each
    qt = 31 - (cid >> 1);
    chunk = cid & 1;
    const int tmid = qt + 1;           // half of 2qt+2 kv32-tiles
    t0 = chunk ? tmid : 0;
    t1 = chunk ? (2 * qt + 2) : tmid;
  } else {                             // qt64 0..7: single
    qt = 55 - cid; chunk = -1; t0 = 0; t1 = 2 * qt + 2;
  }
  const int q0 = qt * 64;

  const int tid = threadIdx.x;
  const int lane = tid & 63;
  const int wv = tid >> 6;
  const int l31 = lane & 31;
  const int hi = lane >> 5;

  // Q B-frags for the two 32-row sub-tiles: col=q0+32s+l31, k=16i+8hi+j
  const u16* qp0 = &qs[(size_t)(b * LL + q0 + l31) * HH + 8 * hi];
  const u16* qp1 = qp0 + 32 * HH;
  const short8 qA0 = *(const short8*)(qp0);
  const short8 qA1 = *(const short8*)(qp0 + 16);
  const short8 qA2 = *(const short8*)(qp0 + 32);
  const short8 qA3 = *(const short8*)(qp0 + 48);
  const short8 qB0 = *(const short8*)(qp1);
  const short8 qB1 = *(const short8*)(qp1 + 16);
  const short8 qB2 = *(const short8*)(qp1 + 32);
  const short8 qB3 = *(const short8*)(qp1 + 48);

  float m0 = -1e30f, l0 = 0.0f;        // sub0 state: q-row q0+l31
  float m1 = -1e30f, l1 = 0.0f;        // sub1 state: q-row q0+32+l31
  f32x16 ot00 = {}, ot01 = {}, ot10 = {}, ot11 = {};  // [sub][hb]

  const u16* kbase = &ks[(size_t)(b * LL) * HH + 8 * hi];
  const u16* vb0 = &vsT[(size_t)(b * HH + l31) * LL + 8 * hi];
  const u16* vb1 = vb0 + 32 * LL;

  for (int t = t0 + wv; t < t1; t += 4) {
    const int kv0 = t << 5;
    // ---- K A-frags (shared by both q-subtiles)
    const u16* kp = kbase + (size_t)(kv0 + l31) * HH;
    short8 ka0 = *(const short8*)(kp);
    short8 ka1 = *(const short8*)(kp + 16);
    short8 ka2 = *(const short8*)(kp + 32);
    short8 ka3 = *(const short8*)(kp + 48);
    f32x16 sA = {}, sB = {};
    __builtin_amdgcn_s_setprio(1);
    sA = mfma32(ka0, qA0, sA);
    sA = mfma32(ka1, qA1, sA);
    sA = mfma32(ka2, qA2, sA);
    sA = mfma32(ka3, qA3, sA);
    sB = mfma32(ka0, qB0, sB);
    sB = mfma32(ka1, qB1, sB);
    sB = mfma32(ka2, qB2, sB);
    sB = mfma32(ka3, qB3, sB);
    __builtin_amdgcn_s_setprio(0);
    // ---- V^T A-frags (issue under softmax)
    short8 va00 = *(const short8*)(vb0 + kv0);
    short8 va01 = *(const short8*)(vb0 + kv0 + 16);
    short8 va10 = *(const short8*)(vb1 + kv0);
    short8 va11 = *(const short8*)(vb1 + kv0 + 16);
    // ---- causal masks (kv = kv0 + (e&3)+8*(e>>2)+4*hi; row = q0+32s+l31)
    if (kv0 + 31 > q0) {
      const int thr0 = q0 + l31 - kv0 - 4 * hi;
#pragma unroll
      for (int e = 0; e < 16; ++e)
        if (((e & 3) + 8 * (e >> 2)) > thr0) sA[e] = -1e30f;
    }
    if (kv0 + 31 > q0 + 32) {
      const int thr1 = q0 + 32 + l31 - kv0 - 4 * hi;
#pragma unroll
      for (int e = 0; e < 16; ++e)
        if (((e & 3) + 8 * (e >> 2)) > thr1) sB[e] = -1e30f;
    }
    // ---- softmax sub0
    float pm0 = sA[0];
#pragma unroll
    for (int e = 1; e < 16; ++e) pm0 = fmaxf(pm0, sA[e]);
    pm0 = fmaxf(pm0, __shfl_xor(pm0, 32));
    const float nm0 = fmaxf(fmaxf(m0, pm0), -1e20f);
    const float al0 = exp2x(m0 - nm0);
    float rs0 = 0.0f;
#pragma unroll
    for (int e = 0; e < 16; ++e) {
      float p = exp2x(sA[e] - nm0);
      sA[e] = p;
      rs0 += p;
    }
    rs0 += __shfl_xor(rs0, 32);
    l0 = l0 * al0 + rs0;
    m0 = nm0;
    // ---- softmax sub1
    float pm1 = sB[0];
#pragma unroll
    for (int e = 1; e < 16; ++e) pm1 = fmaxf(pm1, sB[e]);
    pm1 = fmaxf(pm1, __shfl_xor(pm1, 32));
    const float nm1 = fmaxf(fmaxf(m1, pm1), -1e20f);
    const float al1 = exp2x(m1 - nm1);
    float rs1 = 0.0f;
#pragma unroll
    for (int e = 0; e < 16; ++e) {
      float p = exp2x(sB[e] - nm1);
      sB[e] = p;
      rs1 += p;
    }
    rs1 += __shfl_xor(rs1, 32);
    l1 = l1 * al1 + rs1;
    m1 = nm1;
    // ---- pack P (both subs) -> B-frags via cvt_pk + cross-half exchange
    u32 a0x = cvtpk(sA[0], sA[1]),   a0y = cvtpk(sA[2], sA[3]);
    u32 a1x = cvtpk(sA[4], sA[5]),   a1y = cvtpk(sA[6], sA[7]);
    u32 a2x = cvtpk(sA[8], sA[9]),   a2y = cvtpk(sA[10], sA[11]);
    u32 a3x = cvtpk(sA[12], sA[13]), a3y = cvtpk(sA[14], sA[15]);
    u32 b0x = cvtpk(sB[0], sB[1]),   b0y = cvtpk(sB[2], sB[3]);
    u32 b1x = cvtpk(sB[4], sB[5]),   b1y = cvtpk(sB[6], sB[7]);
    u32 b2x = cvtpk(sB[8], sB[9]),   b2y = cvtpk(sB[10], sB[11]);
    u32 b3x = cvtpk(sB[12], sB[13]), b3y = cvtpk(sB[14], sB[15]);
    u32 xa0x = __shfl_xor(a0x, 32), xa0y = __shfl_xor(a0y, 32);
    u32 xa1x = __shfl_xor(a1x, 32), xa1y = __shfl_xor(a1y, 32);
    u32 xa2x = __shfl_xor(a2x, 32), xa2y = __shfl_xor(a2y, 32);
    u32 xa3x = __shfl_xor(a3x, 32), xa3y = __shfl_xor(a3y, 32);
    u32 xb0x = __shfl_xor(b0x, 32), xb0y = __shfl_xor(b0y, 32);
    u32 xb1x = __shfl_xor(b1x, 32), xb1y = __shfl_xor(b1y, 32);
    u32 xb2x = __shfl_xor(b2x, 32), xb2y = __shfl_xor(b2y, 32);
    u32 xb3x = __shfl_xor(b3x, 32), xb3y = __shfl_xor(b3y, 32);
    u32x4 wA0 = { hi ? xa1x : a0x, hi ? xa1y : a0y,
                  hi ? a1x : xa0x, hi ? a1y : xa0y };
    u32x4 wA1 = { hi ? xa3x : a2x, hi ? xa3y : a2y,
                  hi ? a3x : xa2x, hi ? a3y : xa2y };
    u32x4 wB0 = { hi ? xb1x : b0x, hi ? xb1y : b0y,
                  hi ? b1x : xb0x, hi ? b1y : xb0y };
    u32x4 wB1 = { hi ? xb3x : b2x, hi ? xb3y : b2y,
                  hi ? b3x : xb2x, hi ? b3y : xb2y };
    short8 pbA0 = __builtin_bit_cast(short8, wA0);
    short8 pbA1 = __builtin_bit_cast(short8, wA1);
    short8 pbB0 = __builtin_bit_cast(short8, wB0);
    short8 pbB1 = __builtin_bit_cast(short8, wB1);
    // ---- rescale O^T (in-lane: q-col = 32s + l31) and accumulate PV
#pragma unroll
    for (int e = 0; e < 16; ++e) {
      ot00[e] *= al0; ot01[e] *= al0;
      ot10[e] *= al1; ot11[e] *= al1;
    }
    __builtin_amdgcn_s_setprio(1);
    ot00 = mfma32(va00, pbA0, ot00);
    ot00 = mfma32(va01, pbA1, ot00);
    ot01 = mfma32(va10, pbA0, ot01);
    ot01 = mfma32(va11, pbA1, ot01);
    ot10 = mfma32(va00, pbB0, ot10);
    ot10 = mfma32(va01, pbB1, ot10);
    ot11 = mfma32(va10, pbB0, ot11);
    ot11 = mfma32(va11, pbB1, ot11);
    __builtin_amdgcn_s_setprio(0);
  }

  // ---- per-wave partials to LDS (stride 65: conflict-free)
#pragma unroll
  for (int e = 0; e < 16; ++e) {
    const int h = (e & 3) + 8 * (e >> 2) + 4 * hi;
    oM[wv][l31 * 65 + h] = ot00[e];
    oM[wv][l31 * 65 + 32 + h] = ot01[e];
    oM[wv][(32 + l31) * 65 + h] = ot10[e];
    oM[wv][(32 + l31) * 65 + 32 + h] = ot11[e];
  }
  if (hi == 0) {
    ml[wv][0][l31] = m0;
    ml[wv][1][l31] = l0;
    ml[wv][0][32 + l31] = m1;
    ml[wv][1][32 + l31] = l1;
  }
  __syncthreads();

  // ---- merge 4 waves: thread = (row 0..63, 16 h-cols)
  {
    const int row = tid >> 2;
    const int hq = (tid & 3) * 16;
    float M = ml[0][0][row];
#pragma unroll
    for (int w = 1; w < 4; ++w) M = fmaxf(M, ml[w][0][row]);
    float L = 0.0f;
    float O[16] = {};
#pragma unroll
    for (int w = 0; w < 4; ++w) {
      const float aw = exp2x(ml[w][0][row] - M);
      L += ml[w][1][row] * aw;
#pragma unroll
      for (int j = 0; j < 16; ++j)
        O[j] += oM[w][row * 65 + hq + j] * aw;
    }
    if (chunk < 0) {
      const float inv = 1.0f / L;
      float* op = &out[(size_t)(b * LL + q0 + row) * HH + hq];
#pragma unroll
      for (int j4 = 0; j4 < 4; ++j4) {
        float4 r = { O[4 * j4] * inv, O[4 * j4 + 1] * inv,
                     O[4 * j4 + 2] * inv, O[4 * j4 + 3] * inv };
        *(float4*)(op + 4 * j4) = r;
      }
    } else {
      float* pp = part + (size_t)((b * 24 + (qt - 8)) * 2 + chunk) * PART64;
      if (hq == 0) { pp[row] = M; pp[64 + row] = L; }
      float* od = &pp[128 + row * 64 + hq];
#pragma unroll
      for (int j4 = 0; j4 < 4; ++j4) {
        float4 r = { O[4 * j4], O[4 * j4 + 1], O[4 * j4 + 2], O[4 * j4 + 3] };
        *(float4*)(od + 4 * j4) = r;
      }
    }
  }
}

// ---------------------------------------------------------------------------
// Kernel 3: merge the 2 kv-chunk partials for q-tiles 8..31 (64-row tiles).
// ---------------------------------------------------------------------------
__global__ __launch_bounds__(256) void attn_merge(const float* __restrict__ part,
                                                  float* __restrict__ out) {
  const int bi = blockIdx.x;           // [0, 192) = b*24 + qi
  const int b = bi / 24;
  const int qi = bi % 24;              // qt64 = 8 + qi
  const float* p0 = part + (size_t)((b * 24 + qi) * 2 + 0) * PART64;
  const float* p1 = part + (size_t)((b * 24 + qi) * 2 + 1) * PART64;
  const int row = threadIdx.x >> 2;    // 0..63
  const int hq = (threadIdx.x & 3) * 16;
  const float m0 = p0[row], l0 = p0[64 + row];
  const float m1 = p1[row], l1 = p1[64 + row];
  const float M = fmaxf(m0, m1);
  const float a0 = exp2x(m0 - M), a1 = exp2x(m1 - M);
  const float inv = 1.0f / (l0 * a0 + l1 * a1);
  const float* o0 = &p0[128 + row * 64 + hq];
  const float* o1 = &p1[128 + row * 64 + hq];
  float* op = &out[(size_t)(b * LL + (8 + qi) * 64 + row) * HH + hq];
#pragma unroll
  for (int j4 = 0; j4 < 4; ++j4) {
    float4 A = *(const float4*)(o0 + 4 * j4);
    float4 B = *(const float4*)(o1 + 4 * j4);
    float4 r = { (A.x * a0 + B.x * a1) * inv, (A.y * a0 + B.y * a1) * inv,
                 (A.z * a0 + B.z * a1) * inv, (A.w * a0 + B.w * a1) * inv };
    *(float4*)(op + 4 * j4) = r;
  }
}

extern "C" void kernel_launch(void* const* d_in, const int* in_sizes, int n_in,
                              void* d_out, int out_size, void* d_ws, size_t ws_size,
                              hipStream_t stream) {
  const float* x  = (const float*)d_in[0];
  const float* Wk = (const float*)d_in[1];
  const float* Wq = (const float*)d_in[2];
  const float* Wv = (const float*)d_in[3];

  u16* qs  = (u16*)d_ws;             // [16384][64] bf16
  u16* ks  = qs + BL * HH;           // [16384][64] bf16
  u16* vsT = ks + BL * HH;           // [8][64][2048] bf16 (V transposed)
  u16* wtp = vsT + BL * HH;          // [384][512] bf16 (W in frag order)
  float* part = (float*)(wtp + 384 * 512);  // [8*24][2][PART64] f32

  wtp_pack<<<96, 256, 0, stream>>>(Wq, Wk, Wv, wtp);
  qkv_proj<<<BL / 64, 512, 0, stream>>>(x, wtp, qs, ks, vsT);
  attn<<<56 * BQ, 256, 0, stream>>>(qs, ks, vsT, (float*)d_out, part);
  attn_merge<<<192, 256, 0, stream>>>(part, (float*)d_out);
}